// Round 8
// baseline (551.127 us; speedup 1.0000x reference)
//
#include <hip/hip_runtime.h>
#include <hip/hip_bf16.h>
#include <stdint.h>
#include <math.h>

#define NN 50000
#define DD 128
#define EE 500000
#define ROWT 1563   // ceil(NN/32)

typedef __attribute__((ext_vector_type(8))) short bfx8;
typedef __attribute__((ext_vector_type(4))) short bfx4;
typedef __attribute__((ext_vector_type(4))) float f32x4;
typedef unsigned short u16;

static __device__ __forceinline__ short f2bf(float f) {
  union { float f; uint32_t u; } v; v.f = f;
  uint32_t r = (v.u + 0x7fffu + ((v.u >> 16) & 1u)) >> 16;
  return (short)r;
}
static __device__ __forceinline__ float bf2f(short b) {
  union { uint32_t u; float f; } v; v.u = ((uint32_t)(uint16_t)b) << 16;
  return v.f;
}

// A-fragment from global bf16 [rows][128]
static __device__ __forceinline__ bfx8 load_frag_clamp(const short* base, int row0, int k0, int lane) {
  int r = row0 + (lane & 15);
  if (r >= NN) r = NN - 1;
  int k = k0 + ((lane >> 4) << 3);
  return *reinterpret_cast<const bfx8*>(base + (size_t)r * DD + k);
}
// B-fragment from packed weights: [ct][ks][64 lanes][8]
static __device__ __forceinline__ bfx8 load_pk(const short* p, int ct, int ks, int lane) {
  return *reinterpret_cast<const bfx8*>(p + ((((size_t)ct * 4 + ks) * 64 + lane) << 3));
}

// ---------------- convert fp32 -> bf16 (x_a, x_b) ----------------
struct ConvJobs { const float* src[2]; short* dst[2]; };

__global__ __launch_bounds__(256) void k_convert(ConvJobs jobs) {
  int j = blockIdx.y;
  const float* s = jobs.src[j];
  short* d = jobs.dst[j];
  int i = (blockIdx.x * 256 + threadIdx.x) * 4;
  if (i >= NN * DD) return;
  f32x4 v = *reinterpret_cast<const f32x4*>(s + i);
  bfx4 o;
  o[0]=f2bf(v[0]); o[1]=f2bf(v[1]); o[2]=f2bf(v[2]); o[3]=f2bf(v[3]);
  *reinterpret_cast<bfx4*>(d + i) = o;
}

// ------- P = A[384,128] @ B[128,128], written directly in packed fragment layout (bf16) -------
struct CombJobs { const float* A[6]; const float* B[6]; short* out[6]; };

__global__ __launch_bounds__(256) void k_comb(CombJobs cj) {
  int e = blockIdx.y;
  const float* A = cj.A[e];
  const float* B = cj.B[e];
  short* out = cj.out[e];
  int tid = blockIdx.x * 256 + threadIdx.x;   // 49152 = 384*128
  int i = tid >> 7, j = tid & 127;            // P[i][j]
  float acc = 0.f;
  #pragma unroll 4
  for (int k = 0; k < 128; ++k) acc += A[i * 128 + k] * B[k * 128 + j];
  int ct = i >> 4;
  int lane = (i & 15) | ((((j & 31) >> 3)) << 4);
  int ks = j >> 5;
  int elem = j & 7;
  out[(((size_t)(ct * 4 + ks) * 64 + lane) << 3) + elem] = f2bf(acc);
}

// ---------------- pack f32 matrix [R][128] into fragment layout bf16 ----------------
struct PackJobs { const float* src[3]; short* dst[3]; int nct[3]; };

__global__ __launch_bounds__(256) void k_pack(PackJobs pj) {
  int j = blockIdx.y;
  int tid = blockIdx.x * 256 + threadIdx.x;
  if (tid >= pj.nct[j] * 256) return;
  int lane = tid & 63, ks = (tid >> 6) & 3, ct = tid >> 8;
  const float* s = pj.src[j] + (size_t)(ct * 16 + (lane & 15)) * 128 + ks * 32 + ((lane >> 4) << 3);
  bfx8 o;
  #pragma unroll
  for (int i = 0; i < 8; ++i) o[i] = f2bf(s[i]);
  *reinterpret_cast<bfx8*>(pj.dst[j] + ((size_t)tid << 3)) = o;
}

// ---------------- CSR build (batched over 3 edge types) ----------------
struct CsrArgs { const int* edge[3]; int* counts[3]; int* offs[3]; u16* bucket[3]; };

__global__ __launch_bounds__(256) void k_hist(CsrArgs a) {
  int t = blockIdx.y;
  int tid = blockIdx.x * 256 + threadIdx.x;
  if (tid >= EE) return;
  atomicAdd(&a.counts[t][a.edge[t][EE + tid]], 1);
}

__global__ __launch_bounds__(1024) void k_scan(CsrArgs a) {
  const int* counts = a.counts[blockIdx.x];
  int* offs = a.offs[blockIdx.x];
  __shared__ int lds[1024];
  const int C = (NN + 1023) / 1024;   // 49
  int t = threadIdx.x;
  int base = t * C;
  int sum = 0;
  for (int i = 0; i < C; ++i) { int idx = base + i; if (idx < NN) sum += counts[idx]; }
  lds[t] = sum;
  __syncthreads();
  for (int off = 1; off < 1024; off <<= 1) {
    int v = (t >= off) ? lds[t - off] : 0;
    __syncthreads();
    lds[t] += v;
    __syncthreads();
  }
  int excl = lds[t] - sum;
  for (int i = 0; i < C; ++i) {
    int idx = base + i;
    if (idx < NN) { offs[idx] = excl; excl += counts[idx]; }
  }
}

__global__ __launch_bounds__(256) void k_fill(CsrArgs a) {
  int t = blockIdx.y;
  int tid = blockIdx.x * 256 + threadIdx.x;
  if (tid >= EE) return;
  int tgt = a.edge[t][EE + tid];
  int src = a.edge[t][tid];
  int pos = atomicAdd(&a.offs[t][tgt], 1);
  a.bucket[t][pos] = (u16)src;
}

// ---------------- gather: aggX[row] = sum of x rows (bf16 out, high occupancy) ----------------
struct GArgs {
  const int* offs[3]; const u16* bkt[3];
  const short* xsrc[3]; short* agg[3];
};

__global__ __launch_bounds__(256) void k_gather(GArgs a) {
  const int ty = blockIdx.y;
  const int* __restrict__ offs = a.offs[ty];
  const u16* __restrict__ bucket = a.bkt[ty];
  const short* __restrict__ xsrc = a.xsrc[ty];
  short* __restrict__ agg = a.agg[ty];
  int tid = threadIdx.x;
  int row = blockIdx.x * 32 + (tid >> 3);
  if (row >= NN) return;
  int c0 = (tid & 7) * 16;
  int start = row ? offs[row - 1] : 0;
  int end = offs[row];
  f32x4 s0 = (f32x4)(0.f), s1 = (f32x4)(0.f), s2 = (f32x4)(0.f), s3 = (f32x4)(0.f);
  int i = start;
  for (; i + 4 <= end; i += 4) {
    int e0 = bucket[i], e1 = bucket[i + 1], e2 = bucket[i + 2], e3 = bucket[i + 3];
    const short* p0 = xsrc + (size_t)e0 * DD + c0;
    const short* p1 = xsrc + (size_t)e1 * DD + c0;
    const short* p2 = xsrc + (size_t)e2 * DD + c0;
    const short* p3 = xsrc + (size_t)e3 * DD + c0;
    bfx8 u0 = *reinterpret_cast<const bfx8*>(p0), v0 = *reinterpret_cast<const bfx8*>(p0 + 8);
    bfx8 u1 = *reinterpret_cast<const bfx8*>(p1), v1 = *reinterpret_cast<const bfx8*>(p1 + 8);
    bfx8 u2 = *reinterpret_cast<const bfx8*>(p2), v2 = *reinterpret_cast<const bfx8*>(p2 + 8);
    bfx8 u3 = *reinterpret_cast<const bfx8*>(p3), v3 = *reinterpret_cast<const bfx8*>(p3 + 8);
    #pragma unroll
    for (int j = 0; j < 4; ++j) {
      s0[j] += bf2f(u0[j]) + bf2f(u1[j]) + bf2f(u2[j]) + bf2f(u3[j]);
      s1[j] += bf2f(u0[4+j]) + bf2f(u1[4+j]) + bf2f(u2[4+j]) + bf2f(u3[4+j]);
      s2[j] += bf2f(v0[j]) + bf2f(v1[j]) + bf2f(v2[j]) + bf2f(v3[j]);
      s3[j] += bf2f(v0[4+j]) + bf2f(v1[4+j]) + bf2f(v2[4+j]) + bf2f(v3[4+j]);
    }
  }
  for (; i < end; ++i) {
    const short* p = xsrc + (size_t)bucket[i] * DD + c0;
    bfx8 u = *reinterpret_cast<const bfx8*>(p), v = *reinterpret_cast<const bfx8*>(p + 8);
    #pragma unroll
    for (int j = 0; j < 4; ++j) {
      s0[j] += bf2f(u[j]); s1[j] += bf2f(u[4+j]);
      s2[j] += bf2f(v[j]); s3[j] += bf2f(v[4+j]);
    }
  }
  short* d = agg + (size_t)row * DD + c0;
  bfx8 o0, o1;
  #pragma unroll
  for (int j = 0; j < 4; ++j) {
    o0[j] = f2bf(s0[j]); o0[4+j] = f2bf(s1[j]);
    o1[j] = f2bf(s2[j]); o1[4+j] = f2bf(s3[j]);
  }
  *reinterpret_cast<bfx8*>(d) = o0;
  *reinterpret_cast<bfx8*>(d + 8) = o1;
}

// ---------------- GEMM + GRU, no LDS, no syncthreads ----------------
// h  = aggX @ Ws^T            (f32 in regs, fragment mapping == epilogue mapping)
// gi = xt @ comb^T + bih      (comb  = wih @ Wt)
// gh = aggX @ whhs^T + bhh    (whhs  = whh @ Ws)
struct GGArgs {
  const short* aggX[2]; const short* xt[2];
  const short* wsp[2]; const short* combp[2]; const short* whhsp[2];
  const float* bih[2]; const float* bhh[2];
  float* out[2]; int mode[2];
};

__global__ __launch_bounds__(256) void k_ggru(GGArgs a) {
  const int ty = blockIdx.y;
  const int wave = threadIdx.x >> 6, lane = threadIdx.x & 63;
  const int rbase = blockIdx.x * 32;
  const short* __restrict__ aggX = a.aggX[ty];
  const short* __restrict__ xt = a.xt[ty];
  const short* wsp = a.wsp[ty];
  const short* combp = a.combp[ty];
  const short* whhsp = a.whhsp[ty];

  f32x4 h[2][2], ai[2][2][3], ah[2][2][3];
  #pragma unroll
  for (int rf = 0; rf < 2; ++rf)
    #pragma unroll
    for (int c = 0; c < 2; ++c) {
      h[rf][c] = (f32x4)(0.f);
      #pragma unroll
      for (int g = 0; g < 3; ++g) { ai[rf][c][g] = (f32x4)(0.f); ah[rf][c][g] = (f32x4)(0.f); }
    }

  #pragma unroll
  for (int ks = 0; ks < 4; ++ks) {
    bfx8 x0 = load_frag_clamp(xt,   rbase,      ks * 32, lane);
    bfx8 x1 = load_frag_clamp(xt,   rbase + 16, ks * 32, lane);
    bfx8 g0 = load_frag_clamp(aggX, rbase,      ks * 32, lane);
    bfx8 g1 = load_frag_clamp(aggX, rbase + 16, ks * 32, lane);
    #pragma unroll
    for (int c = 0; c < 2; ++c) {
      bfx8 b = load_pk(wsp, wave * 2 + c, ks, lane);
      h[0][c] = __builtin_amdgcn_mfma_f32_16x16x32_bf16(g0, b, h[0][c], 0, 0, 0);
      h[1][c] = __builtin_amdgcn_mfma_f32_16x16x32_bf16(g1, b, h[1][c], 0, 0, 0);
    }
    #pragma unroll
    for (int g = 0; g < 3; ++g)
      #pragma unroll
      for (int c = 0; c < 2; ++c) {
        int ct = g * 8 + wave * 2 + c;
        bfx8 bi = load_pk(combp, ct, ks, lane);
        bfx8 bh = load_pk(whhsp, ct, ks, lane);
        ai[0][c][g] = __builtin_amdgcn_mfma_f32_16x16x32_bf16(x0, bi, ai[0][c][g], 0, 0, 0);
        ai[1][c][g] = __builtin_amdgcn_mfma_f32_16x16x32_bf16(x1, bi, ai[1][c][g], 0, 0, 0);
        ah[0][c][g] = __builtin_amdgcn_mfma_f32_16x16x32_bf16(g0, bh, ah[0][c][g], 0, 0, 0);
        ah[1][c][g] = __builtin_amdgcn_mfma_f32_16x16x32_bf16(g1, bh, ah[1][c][g], 0, 0, 0);
      }
  }

  const float* bih = a.bih[ty];
  const float* bhh = a.bhh[ty];
  float* out = a.out[ty];
  const int mode = a.mode[ty];
  const int lq = (lane >> 4) << 2;
  #pragma unroll
  for (int c = 0; c < 2; ++c) {
    int col = wave * 32 + c * 16 + (lane & 15);
    float bir = bih[col], biz = bih[128 + col], bin = bih[256 + col];
    float bhr = bhh[col], bhz = bhh[128 + col], bhn = bhh[256 + col];
    #pragma unroll
    for (int rf = 0; rf < 2; ++rf)
      #pragma unroll
      for (int q = 0; q < 4; ++q) {
        int r = rbase + rf * 16 + lq + q;
        if (r >= NN) continue;
        float ir = ai[rf][c][0][q] + bir, iz = ai[rf][c][1][q] + biz, in = ai[rf][c][2][q] + bin;
        float hr = ah[rf][c][0][q] + bhr, hz = ah[rf][c][1][q] + bhz, hn = ah[rf][c][2][q] + bhn;
        float rr = 1.f / (1.f + expf(-(ir + hr)));
        float zz = 1.f / (1.f + expf(-(iz + hz)));
        float nn = tanhf(in + rr * hn);
        float hh = h[rf][c][q];
        float res = (1.f - zz) * nn + zz * hh;
        size_t o = (size_t)r * DD + col;
        if (mode == 0)      out[o] = fmaxf(res, 0.f);
        else if (mode == 1) out[o] = res;
        else                out[o] = fmaxf((out[o] + res) * 0.5f, 0.f);
      }
  }
}

extern "C" void kernel_launch(void* const* d_in, const int* in_sizes, int n_in,
                              void* d_out, int out_size, void* d_ws, size_t ws_size,
                              hipStream_t stream) {
  const float* x_a = (const float*)d_in[0];
  const float* x_b = (const float*)d_in[1];
  const int* edges[3] = {(const int*)d_in[2], (const int*)d_in[3], (const int*)d_in[4]};
  const float *Ws[3], *Wt[3], *wih[3], *whh[3], *bih[3], *bhh[3];
  for (int e = 0; e < 3; ++e) {
    int b = 5 + e * 6;
    Ws[e]  = (const float*)d_in[b + 0];
    Wt[e]  = (const float*)d_in[b + 1];
    wih[e] = (const float*)d_in[b + 2];
    whh[e] = (const float*)d_in[b + 3];
    bih[e] = (const float*)d_in[b + 4];
    bhh[e] = (const float*)d_in[b + 5];
  }

  // workspace layout (~69 MB)
  char* ws = (char*)d_ws;
  short* xa_bf  = (short*)ws;                        // 12.8 MB
  short* xb_bf  = (short*)(ws + 12800000);           // 12.8 MB
  short* aggX   = (short*)(ws + 25600000);           // 3 x 12.8 MB
  int*   counts = (int*)(ws + 64000000);             // 3 x 200 KB
  int*   offs   = (int*)(ws + 64600000);             // 3 x 200 KB
  u16*   bucket = (u16*)(ws + 65200000);             // 3 x 1 MB
  short* pk     = (short*)(ws + 68200000);           // 3 x 224 KB
  short *wsp[3], *combp[3], *whhsp[3];
  short* aggp[3];
  int *countsp[3], *offsp[3]; u16* bktp[3];
  for (int e = 0; e < 3; ++e) {
    short* base = pk + (size_t)e * 114688;
    wsp[e] = base; combp[e] = base + 16384; whhsp[e] = base + 65536;
    aggp[e]   = aggX + (size_t)e * NN * DD;
    countsp[e] = counts + (size_t)e * 50000;
    offsp[e]   = offs + (size_t)e * 50000;
    bktp[e]    = bucket + (size_t)e * 500000;
  }

  // 1) convert x_a, x_b to bf16
  ConvJobs cj;
  cj.src[0] = x_a; cj.dst[0] = xa_bf;
  cj.src[1] = x_b; cj.dst[1] = xb_bf;
  hipLaunchKernelGGL(k_convert, dim3(6250, 2), dim3(256), 0, stream, cj);

  // 2) comb = wih@Wt, whhs = whh@Ws -> packed bf16 (6 jobs)
  CombJobs cb;
  for (int e = 0; e < 3; ++e) {
    cb.A[e] = wih[e];     cb.B[e] = Wt[e]; cb.out[e] = combp[e];
    cb.A[3 + e] = whh[e]; cb.B[3 + e] = Ws[e]; cb.out[3 + e] = whhsp[e];
  }
  hipLaunchKernelGGL(k_comb, dim3(192, 6), dim3(256), 0, stream, cb);

  // 3) pack Ws
  PackJobs pj;
  for (int e = 0; e < 3; ++e) { pj.src[e] = Ws[e]; pj.dst[e] = wsp[e]; pj.nct[e] = 8; }
  hipLaunchKernelGGL(k_pack, dim3(8, 3), dim3(256), 0, stream, pj);

  // 4) CSR build
  CsrArgs ca;
  for (int e = 0; e < 3; ++e) {
    ca.edge[e] = edges[e]; ca.counts[e] = countsp[e];
    ca.offs[e] = offsp[e]; ca.bucket[e] = bktp[e];
  }
  (void)hipMemsetAsync(counts, 0, 3 * 50000 * sizeof(int), stream);
  const int EB = (EE + 255) / 256;
  hipLaunchKernelGGL(k_hist, dim3(EB, 3), dim3(256), 0, stream, ca);
  hipLaunchKernelGGL(k_scan, dim3(3), dim3(1024), 0, stream, ca);
  hipLaunchKernelGGL(k_fill, dim3(EB, 3), dim3(256), 0, stream, ca);

  // 5) gather all 3 types (high-occupancy, latency-tolerant)
  GArgs ga;
  const short* srcb[3] = {xa_bf, xb_bf, xb_bf};
  for (int e = 0; e < 3; ++e) {
    ga.offs[e] = offsp[e]; ga.bkt[e] = bktp[e];
    ga.xsrc[e] = srcb[e];  ga.agg[e] = aggp[e];
  }
  hipLaunchKernelGGL(k_gather, dim3(ROWT, 3), dim3(256), 0, stream, ga);

  // 6) GEMM+GRU: dispatch A = {e1 -> out_b, e2 -> out_a raw}; dispatch B = {e3 -> out_a rmw}
  float* out_a = (float*)d_out;
  float* out_b = (float*)d_out + (size_t)NN * DD;

  GGArgs fa;
  fa.aggX[0] = aggp[0]; fa.xt[0] = xb_bf;
  fa.wsp[0] = wsp[0]; fa.combp[0] = combp[0]; fa.whhsp[0] = whhsp[0];
  fa.bih[0] = bih[0]; fa.bhh[0] = bhh[0];
  fa.out[0] = out_b; fa.mode[0] = 0;
  fa.aggX[1] = aggp[1]; fa.xt[1] = xa_bf;
  fa.wsp[1] = wsp[1]; fa.combp[1] = combp[1]; fa.whhsp[1] = whhsp[1];
  fa.bih[1] = bih[1]; fa.bhh[1] = bhh[1];
  fa.out[1] = out_a; fa.mode[1] = 1;
  hipLaunchKernelGGL(k_ggru, dim3(ROWT, 2), dim3(256), 0, stream, fa);

  GGArgs fb;
  fb.aggX[0] = aggp[2]; fb.xt[0] = xa_bf;
  fb.wsp[0] = wsp[2]; fb.combp[0] = combp[2]; fb.whhsp[0] = whhsp[2];
  fb.bih[0] = bih[2]; fb.bhh[0] = bhh[2];
  fb.out[0] = out_a; fb.mode[0] = 2;
  fb.aggX[1] = fb.aggX[0]; fb.xt[1] = fb.xt[0];
  fb.wsp[1] = fb.wsp[0]; fb.combp[1] = fb.combp[0]; fb.whhsp[1] = fb.whhsp[0];
  fb.bih[1] = fb.bih[0]; fb.bhh[1] = fb.bhh[0];
  fb.out[1] = fb.out[0]; fb.mode[1] = fb.mode[0];
  hipLaunchKernelGGL(k_ggru, dim3(ROWT, 1), dim3(256), 0, stream, fb);
}

// Round 9
// 453.359 us; speedup vs baseline: 1.2157x; 1.2157x over previous
//
#include <hip/hip_runtime.h>
#include <hip/hip_bf16.h>
#include <stdint.h>
#include <math.h>

#define NN 50000
#define DD 128
#define EE 500000
#define ROWT 1563   // ceil(NN/32)

typedef __attribute__((ext_vector_type(8))) short bfx8;
typedef __attribute__((ext_vector_type(4))) short bfx4;
typedef __attribute__((ext_vector_type(4))) float f32x4;
typedef unsigned short u16;

static __device__ __forceinline__ short f2bf(float f) {
  union { float f; uint32_t u; } v; v.f = f;
  uint32_t r = (v.u + 0x7fffu + ((v.u >> 16) & 1u)) >> 16;
  return (short)r;
}
static __device__ __forceinline__ float bf2f(short b) {
  union { uint32_t u; float f; } v; v.u = ((uint32_t)(uint16_t)b) << 16;
  return v.f;
}

// A-fragment from global bf16 [rows][128]
static __device__ __forceinline__ bfx8 load_frag_clamp(const short* base, int row0, int k0, int lane) {
  int r = row0 + (lane & 15);
  if (r >= NN) r = NN - 1;
  int k = k0 + ((lane >> 4) << 3);
  return *reinterpret_cast<const bfx8*>(base + (size_t)r * DD + k);
}
// B-fragment from packed weights: [ct][ks][64 lanes][8]
static __device__ __forceinline__ bfx8 load_pk(const short* p, int ct, int ks, int lane) {
  return *reinterpret_cast<const bfx8*>(p + ((((size_t)ct * 4 + ks) * 64 + lane) << 3));
}

// ---------------- convert fp32 -> bf16 (x_a, x_b) ----------------
struct ConvJobs { const float* src[2]; short* dst[2]; };

__global__ __launch_bounds__(256) void k_convert(ConvJobs jobs) {
  int j = blockIdx.y;
  const float* s = jobs.src[j];
  short* d = jobs.dst[j];
  int i = (blockIdx.x * 256 + threadIdx.x) * 4;
  if (i >= NN * DD) return;
  f32x4 v = *reinterpret_cast<const f32x4*>(s + i);
  bfx4 o;
  o[0]=f2bf(v[0]); o[1]=f2bf(v[1]); o[2]=f2bf(v[2]); o[3]=f2bf(v[3]);
  *reinterpret_cast<bfx4*>(d + i) = o;
}

// ------- P = A[384,128] @ B[128,128], written directly in packed fragment layout (bf16) -------
struct CombJobs { const float* A[6]; const float* B[6]; short* out[6]; };

__global__ __launch_bounds__(256) void k_comb(CombJobs cj) {
  int e = blockIdx.y;
  const float* A = cj.A[e];
  const float* B = cj.B[e];
  short* out = cj.out[e];
  int tid = blockIdx.x * 256 + threadIdx.x;   // 49152 = 384*128
  int i = tid >> 7, j = tid & 127;            // P[i][j]
  float acc = 0.f;
  #pragma unroll 4
  for (int k = 0; k < 128; ++k) acc += A[i * 128 + k] * B[k * 128 + j];
  int ct = i >> 4;
  int lane = (i & 15) | ((((j & 31) >> 3)) << 4);
  int ks = j >> 5;
  int elem = j & 7;
  out[(((size_t)(ct * 4 + ks) * 64 + lane) << 3) + elem] = f2bf(acc);
}

// ---------------- pack f32 matrix [R][128] into fragment layout bf16 ----------------
struct PackJobs { const float* src[3]; short* dst[3]; int nct[3]; };

__global__ __launch_bounds__(256) void k_pack(PackJobs pj) {
  int j = blockIdx.y;
  int tid = blockIdx.x * 256 + threadIdx.x;
  if (tid >= pj.nct[j] * 256) return;
  int lane = tid & 63, ks = (tid >> 6) & 3, ct = tid >> 8;
  const float* s = pj.src[j] + (size_t)(ct * 16 + (lane & 15)) * 128 + ks * 32 + ((lane >> 4) << 3);
  bfx8 o;
  #pragma unroll
  for (int i = 0; i < 8; ++i) o[i] = f2bf(s[i]);
  *reinterpret_cast<bfx8*>(pj.dst[j] + ((size_t)tid << 3)) = o;
}

// ---------------- CSR build (batched over 3 edge types) ----------------
struct CsrArgs { const int* edge[3]; int* counts[3]; int* offs[3]; u16* bucket[3]; };

__global__ __launch_bounds__(256) void k_hist(CsrArgs a) {
  int t = blockIdx.y;
  int tid = blockIdx.x * 256 + threadIdx.x;
  if (tid >= EE) return;
  atomicAdd(&a.counts[t][a.edge[t][EE + tid]], 1);
}

__global__ __launch_bounds__(1024) void k_scan(CsrArgs a) {
  const int* counts = a.counts[blockIdx.x];
  int* offs = a.offs[blockIdx.x];
  __shared__ int lds[1024];
  const int C = (NN + 1023) / 1024;   // 49
  int t = threadIdx.x;
  int base = t * C;
  int sum = 0;
  for (int i = 0; i < C; ++i) { int idx = base + i; if (idx < NN) sum += counts[idx]; }
  lds[t] = sum;
  __syncthreads();
  for (int off = 1; off < 1024; off <<= 1) {
    int v = (t >= off) ? lds[t - off] : 0;
    __syncthreads();
    lds[t] += v;
    __syncthreads();
  }
  int excl = lds[t] - sum;
  for (int i = 0; i < C; ++i) {
    int idx = base + i;
    if (idx < NN) { offs[idx] = excl; excl += counts[idx]; }
  }
}

__global__ __launch_bounds__(256) void k_fill(CsrArgs a) {
  int t = blockIdx.y;
  int tid = blockIdx.x * 256 + threadIdx.x;
  if (tid >= EE) return;
  int tgt = a.edge[t][EE + tid];
  int src = a.edge[t][tid];
  int pos = atomicAdd(&a.offs[t][tgt], 1);
  a.bucket[t][pos] = (u16)src;
}

// ---------------- gather: aggX[row] = sum of x rows (bf16 out, high occupancy) ----------------
struct GArgs {
  const int* offs[3]; const u16* bkt[3];
  const short* xsrc[3]; short* agg[3];
};

__global__ __launch_bounds__(256) void k_gather(GArgs a) {
  const int ty = blockIdx.y;
  const int* __restrict__ offs = a.offs[ty];
  const u16* __restrict__ bucket = a.bkt[ty];
  const short* __restrict__ xsrc = a.xsrc[ty];
  short* __restrict__ agg = a.agg[ty];
  int tid = threadIdx.x;
  int row = blockIdx.x * 32 + (tid >> 3);
  if (row >= NN) return;
  int c0 = (tid & 7) * 16;
  int start = row ? offs[row - 1] : 0;
  int end = offs[row];
  f32x4 s0 = (f32x4)(0.f), s1 = (f32x4)(0.f), s2 = (f32x4)(0.f), s3 = (f32x4)(0.f);
  int i = start;
  for (; i + 4 <= end; i += 4) {
    int e0 = bucket[i], e1 = bucket[i + 1], e2 = bucket[i + 2], e3 = bucket[i + 3];
    const short* p0 = xsrc + (size_t)e0 * DD + c0;
    const short* p1 = xsrc + (size_t)e1 * DD + c0;
    const short* p2 = xsrc + (size_t)e2 * DD + c0;
    const short* p3 = xsrc + (size_t)e3 * DD + c0;
    bfx8 u0 = *reinterpret_cast<const bfx8*>(p0), v0 = *reinterpret_cast<const bfx8*>(p0 + 8);
    bfx8 u1 = *reinterpret_cast<const bfx8*>(p1), v1 = *reinterpret_cast<const bfx8*>(p1 + 8);
    bfx8 u2 = *reinterpret_cast<const bfx8*>(p2), v2 = *reinterpret_cast<const bfx8*>(p2 + 8);
    bfx8 u3 = *reinterpret_cast<const bfx8*>(p3), v3 = *reinterpret_cast<const bfx8*>(p3 + 8);
    #pragma unroll
    for (int j = 0; j < 4; ++j) {
      s0[j] += bf2f(u0[j]) + bf2f(u1[j]) + bf2f(u2[j]) + bf2f(u3[j]);
      s1[j] += bf2f(u0[4+j]) + bf2f(u1[4+j]) + bf2f(u2[4+j]) + bf2f(u3[4+j]);
      s2[j] += bf2f(v0[j]) + bf2f(v1[j]) + bf2f(v2[j]) + bf2f(v3[j]);
      s3[j] += bf2f(v0[4+j]) + bf2f(v1[4+j]) + bf2f(v2[4+j]) + bf2f(v3[4+j]);
    }
  }
  for (; i < end; ++i) {
    const short* p = xsrc + (size_t)bucket[i] * DD + c0;
    bfx8 u = *reinterpret_cast<const bfx8*>(p), v = *reinterpret_cast<const bfx8*>(p + 8);
    #pragma unroll
    for (int j = 0; j < 4; ++j) {
      s0[j] += bf2f(u[j]); s1[j] += bf2f(u[4+j]);
      s2[j] += bf2f(v[j]); s3[j] += bf2f(v[4+j]);
    }
  }
  short* d = agg + (size_t)row * DD + c0;
  bfx8 o0, o1;
  #pragma unroll
  for (int j = 0; j < 4; ++j) {
    o0[j] = f2bf(s0[j]); o0[4+j] = f2bf(s1[j]);
    o1[j] = f2bf(s2[j]); o1[4+j] = f2bf(s3[j]);
  }
  *reinterpret_cast<bfx8*>(d) = o0;
  *reinterpret_cast<bfx8*>(d + 8) = o1;
}

// ---------------- GEMM + GRU, no LDS; block = 32 rows x 64 cols (wave = 16 cols) ----------------
// h  = aggX @ Ws^T ; gi = xt @ comb^T + bih ; gh = aggX @ whhs^T + bhh
struct GGArgs {
  const short* aggX[2]; const short* xt[2];
  const short* wsp[2]; const short* combp[2]; const short* whhsp[2];
  const float* bih[2]; const float* bhh[2];
  float* out[2]; int mode[2];
};

__global__ __launch_bounds__(256) void k_ggru(GGArgs a) {
  const int ty = blockIdx.y;
  const int wave = threadIdx.x >> 6, lane = threadIdx.x & 63;
  const int rbase = (blockIdx.x >> 1) * 32;
  const int colblk = blockIdx.x & 1;
  const int ctw = colblk * 4 + wave;          // this wave's 16-col tile index (0..7)
  const short* __restrict__ aggX = a.aggX[ty];
  const short* __restrict__ xt = a.xt[ty];
  const short* wsp = a.wsp[ty];
  const short* combp = a.combp[ty];
  const short* whhsp = a.whhsp[ty];

  f32x4 h[2], ai[2][3], ah[2][3];
  #pragma unroll
  for (int rf = 0; rf < 2; ++rf) {
    h[rf] = (f32x4)(0.f);
    #pragma unroll
    for (int g = 0; g < 3; ++g) { ai[rf][g] = (f32x4)(0.f); ah[rf][g] = (f32x4)(0.f); }
  }

  #pragma unroll
  for (int ks = 0; ks < 4; ++ks) {
    bfx8 x0 = load_frag_clamp(xt,   rbase,      ks * 32, lane);
    bfx8 x1 = load_frag_clamp(xt,   rbase + 16, ks * 32, lane);
    bfx8 g0 = load_frag_clamp(aggX, rbase,      ks * 32, lane);
    bfx8 g1 = load_frag_clamp(aggX, rbase + 16, ks * 32, lane);
    bfx8 bws = load_pk(wsp, ctw, ks, lane);
    h[0] = __builtin_amdgcn_mfma_f32_16x16x32_bf16(g0, bws, h[0], 0, 0, 0);
    h[1] = __builtin_amdgcn_mfma_f32_16x16x32_bf16(g1, bws, h[1], 0, 0, 0);
    #pragma unroll
    for (int g = 0; g < 3; ++g) {
      int ct = g * 8 + ctw;
      bfx8 bi = load_pk(combp, ct, ks, lane);
      bfx8 bh = load_pk(whhsp, ct, ks, lane);
      ai[0][g] = __builtin_amdgcn_mfma_f32_16x16x32_bf16(x0, bi, ai[0][g], 0, 0, 0);
      ai[1][g] = __builtin_amdgcn_mfma_f32_16x16x32_bf16(x1, bi, ai[1][g], 0, 0, 0);
      ah[0][g] = __builtin_amdgcn_mfma_f32_16x16x32_bf16(g0, bh, ah[0][g], 0, 0, 0);
      ah[1][g] = __builtin_amdgcn_mfma_f32_16x16x32_bf16(g1, bh, ah[1][g], 0, 0, 0);
    }
  }

  const float* bih = a.bih[ty];
  const float* bhh = a.bhh[ty];
  float* out = a.out[ty];
  const int mode = a.mode[ty];
  const int lq = (lane >> 4) << 2;
  const int col = ctw * 16 + (lane & 15);
  const float bir = bih[col], biz = bih[128 + col], bin = bih[256 + col];
  const float bhr = bhh[col], bhz = bhh[128 + col], bhn = bhh[256 + col];
  #pragma unroll
  for (int rf = 0; rf < 2; ++rf)
    #pragma unroll
    for (int q = 0; q < 4; ++q) {
      int r = rbase + rf * 16 + lq + q;
      if (r >= NN) continue;
      float ir = ai[rf][0][q] + bir, iz = ai[rf][1][q] + biz, in = ai[rf][2][q] + bin;
      float hr = ah[rf][0][q] + bhr, hz = ah[rf][1][q] + bhz, hn = ah[rf][2][q] + bhn;
      float rr = 1.f / (1.f + __expf(-(ir + hr)));
      float zz = 1.f / (1.f + __expf(-(iz + hz)));
      float t2 = in + rr * hn;
      float nn = 1.f - 2.f / (__expf(2.f * t2) + 1.f);   // tanh
      float hh = h[rf][q];
      float res = (1.f - zz) * nn + zz * hh;
      size_t o = (size_t)r * DD + col;
      if (mode == 0)      out[o] = fmaxf(res, 0.f);
      else if (mode == 1) out[o] = res;
      else                out[o] = fmaxf((out[o] + res) * 0.5f, 0.f);
    }
}

extern "C" void kernel_launch(void* const* d_in, const int* in_sizes, int n_in,
                              void* d_out, int out_size, void* d_ws, size_t ws_size,
                              hipStream_t stream) {
  const float* x_a = (const float*)d_in[0];
  const float* x_b = (const float*)d_in[1];
  const int* edges[3] = {(const int*)d_in[2], (const int*)d_in[3], (const int*)d_in[4]};
  const float *Ws[3], *Wt[3], *wih[3], *whh[3], *bih[3], *bhh[3];
  for (int e = 0; e < 3; ++e) {
    int b = 5 + e * 6;
    Ws[e]  = (const float*)d_in[b + 0];
    Wt[e]  = (const float*)d_in[b + 1];
    wih[e] = (const float*)d_in[b + 2];
    whh[e] = (const float*)d_in[b + 3];
    bih[e] = (const float*)d_in[b + 4];
    bhh[e] = (const float*)d_in[b + 5];
  }

  // workspace layout (~69 MB)
  char* ws = (char*)d_ws;
  short* xa_bf  = (short*)ws;                        // 12.8 MB
  short* xb_bf  = (short*)(ws + 12800000);           // 12.8 MB
  short* aggX   = (short*)(ws + 25600000);           // 3 x 12.8 MB
  int*   counts = (int*)(ws + 64000000);             // 3 x 200 KB
  int*   offs   = (int*)(ws + 64600000);             // 3 x 200 KB
  u16*   bucket = (u16*)(ws + 65200000);             // 3 x 1 MB
  short* pk     = (short*)(ws + 68200000);           // 3 x 224 KB
  short *wsp[3], *combp[3], *whhsp[3];
  short* aggp[3];
  int *countsp[3], *offsp[3]; u16* bktp[3];
  for (int e = 0; e < 3; ++e) {
    short* base = pk + (size_t)e * 114688;
    wsp[e] = base; combp[e] = base + 16384; whhsp[e] = base + 65536;
    aggp[e]   = aggX + (size_t)e * NN * DD;
    countsp[e] = counts + (size_t)e * 50000;
    offsp[e]   = offs + (size_t)e * 50000;
    bktp[e]    = bucket + (size_t)e * 500000;
  }

  // 1) convert x_a, x_b to bf16
  ConvJobs cj;
  cj.src[0] = x_a; cj.dst[0] = xa_bf;
  cj.src[1] = x_b; cj.dst[1] = xb_bf;
  hipLaunchKernelGGL(k_convert, dim3(6250, 2), dim3(256), 0, stream, cj);

  // 2) comb = wih@Wt, whhs = whh@Ws -> packed bf16 (6 jobs)
  CombJobs cb;
  for (int e = 0; e < 3; ++e) {
    cb.A[e] = wih[e];     cb.B[e] = Wt[e]; cb.out[e] = combp[e];
    cb.A[3 + e] = whh[e]; cb.B[3 + e] = Ws[e]; cb.out[3 + e] = whhsp[e];
  }
  hipLaunchKernelGGL(k_comb, dim3(192, 6), dim3(256), 0, stream, cb);

  // 3) pack Ws
  PackJobs pj;
  for (int e = 0; e < 3; ++e) { pj.src[e] = Ws[e]; pj.dst[e] = wsp[e]; pj.nct[e] = 8; }
  hipLaunchKernelGGL(k_pack, dim3(8, 3), dim3(256), 0, stream, pj);

  // 4) CSR build
  CsrArgs ca;
  for (int e = 0; e < 3; ++e) {
    ca.edge[e] = edges[e]; ca.counts[e] = countsp[e];
    ca.offs[e] = offsp[e]; ca.bucket[e] = bktp[e];
  }
  (void)hipMemsetAsync(counts, 0, 3 * 50000 * sizeof(int), stream);
  const int EB = (EE + 255) / 256;
  hipLaunchKernelGGL(k_hist, dim3(EB, 3), dim3(256), 0, stream, ca);
  hipLaunchKernelGGL(k_scan, dim3(3), dim3(1024), 0, stream, ca);
  hipLaunchKernelGGL(k_fill, dim3(EB, 3), dim3(256), 0, stream, ca);

  // 5) gather all 3 types
  GArgs ga;
  const short* srcb[3] = {xa_bf, xb_bf, xb_bf};
  for (int e = 0; e < 3; ++e) {
    ga.offs[e] = offsp[e]; ga.bkt[e] = bktp[e];
    ga.xsrc[e] = srcb[e];  ga.agg[e] = aggp[e];
  }
  hipLaunchKernelGGL(k_gather, dim3(ROWT, 3), dim3(256), 0, stream, ga);

  // 6) GEMM+GRU: dispatch A = {e1 -> out_b, e2 -> out_a raw}; dispatch B = {e3 -> out_a rmw}
  float* out_a = (float*)d_out;
  float* out_b = (float*)d_out + (size_t)NN * DD;

  GGArgs fa;
  fa.aggX[0] = aggp[0]; fa.xt[0] = xb_bf;
  fa.wsp[0] = wsp[0]; fa.combp[0] = combp[0]; fa.whhsp[0] = whhsp[0];
  fa.bih[0] = bih[0]; fa.bhh[0] = bhh[0];
  fa.out[0] = out_b; fa.mode[0] = 0;
  fa.aggX[1] = aggp[1]; fa.xt[1] = xa_bf;
  fa.wsp[1] = wsp[1]; fa.combp[1] = combp[1]; fa.whhsp[1] = whhsp[1];
  fa.bih[1] = bih[1]; fa.bhh[1] = bhh[1];
  fa.out[1] = out_a; fa.mode[1] = 1;
  hipLaunchKernelGGL(k_ggru, dim3(ROWT * 2, 2), dim3(256), 0, stream, fa);

  GGArgs fb;
  fb.aggX[0] = aggp[2]; fb.xt[0] = xa_bf;
  fb.wsp[0] = wsp[2]; fb.combp[0] = combp[2]; fb.whhsp[0] = whhsp[2];
  fb.bih[0] = bih[2]; fb.bhh[0] = bhh[2];
  fb.out[0] = out_a; fb.mode[0] = 2;
  fb.aggX[1] = fb.aggX[0]; fb.xt[1] = fb.xt[0];
  fb.wsp[1] = fb.wsp[0]; fb.combp[1] = fb.combp[0]; fb.whhsp[1] = fb.whhsp[0];
  fb.bih[1] = fb.bih[0]; fb.bhh[1] = fb.bhh[0];
  fb.out[1] = fb.out[0]; fb.mode[1] = fb.mode[0];
  hipLaunchKernelGGL(k_ggru, dim3(ROWT * 2, 1), dim3(256), 0, stream, fb);
}

// Round 10
// 430.495 us; speedup vs baseline: 1.2802x; 1.0531x over previous
//
#include <hip/hip_runtime.h>
#include <hip/hip_bf16.h>
#include <stdint.h>
#include <math.h>

#define NN 50000
#define DD 128
#define EE 500000
#define ROWT 1563   // ceil(NN/32)

typedef __attribute__((ext_vector_type(8))) short bfx8;
typedef __attribute__((ext_vector_type(4))) short bfx4;
typedef __attribute__((ext_vector_type(4))) float f32x4;
typedef unsigned short u16;

static __device__ __forceinline__ short f2bf(float f) {
  union { float f; uint32_t u; } v; v.f = f;
  uint32_t r = (v.u + 0x7fffu + ((v.u >> 16) & 1u)) >> 16;
  return (short)r;
}
static __device__ __forceinline__ float bf2f(short b) {
  union { uint32_t u; float f; } v; v.u = ((uint32_t)(uint16_t)b) << 16;
  return v.f;
}

// A-fragment from global bf16 [rows][128]
static __device__ __forceinline__ bfx8 load_frag_clamp(const short* base, int row0, int k0, int lane) {
  int r = row0 + (lane & 15);
  if (r >= NN) r = NN - 1;
  int k = k0 + ((lane >> 4) << 3);
  return *reinterpret_cast<const bfx8*>(base + (size_t)r * DD + k);
}
// B-fragment from packed weights: [ct][ks][64 lanes][8]
static __device__ __forceinline__ bfx8 load_pk(const short* p, int ct, int ks, int lane) {
  return *reinterpret_cast<const bfx8*>(p + ((((size_t)ct * 4 + ks) * 64 + lane) << 3));
}

// ---------------- convert fp32 -> bf16 (x_a, x_b) ----------------
struct ConvJobs { const float* src[2]; short* dst[2]; };

__global__ __launch_bounds__(256) void k_convert(ConvJobs jobs) {
  int j = blockIdx.y;
  const float* s = jobs.src[j];
  short* d = jobs.dst[j];
  int i = (blockIdx.x * 256 + threadIdx.x) * 4;
  if (i >= NN * DD) return;
  f32x4 v = *reinterpret_cast<const f32x4*>(s + i);
  bfx4 o;
  o[0]=f2bf(v[0]); o[1]=f2bf(v[1]); o[2]=f2bf(v[2]); o[3]=f2bf(v[3]);
  *reinterpret_cast<bfx4*>(d + i) = o;
}

// ------- P = A[384,128] @ B[128,128], written directly in packed fragment layout (bf16) -------
struct CombJobs { const float* A[6]; const float* B[6]; short* out[6]; };

__global__ __launch_bounds__(256) void k_comb(CombJobs cj) {
  int e = blockIdx.y;
  const float* A = cj.A[e];
  const float* B = cj.B[e];
  short* out = cj.out[e];
  int tid = blockIdx.x * 256 + threadIdx.x;   // 49152 = 384*128
  int i = tid >> 7, j = tid & 127;            // P[i][j]
  float acc = 0.f;
  #pragma unroll 4
  for (int k = 0; k < 128; ++k) acc += A[i * 128 + k] * B[k * 128 + j];
  int ct = i >> 4;
  int lane = (i & 15) | ((((j & 31) >> 3)) << 4);
  int ks = j >> 5;
  int elem = j & 7;
  out[(((size_t)(ct * 4 + ks) * 64 + lane) << 3) + elem] = f2bf(acc);
}

// ---------------- pack f32 matrix [R][128] into fragment layout bf16 ----------------
struct PackJobs { const float* src[3]; short* dst[3]; int nct[3]; };

__global__ __launch_bounds__(256) void k_pack(PackJobs pj) {
  int j = blockIdx.y;
  int tid = blockIdx.x * 256 + threadIdx.x;
  if (tid >= pj.nct[j] * 256) return;
  int lane = tid & 63, ks = (tid >> 6) & 3, ct = tid >> 8;
  const float* s = pj.src[j] + (size_t)(ct * 16 + (lane & 15)) * 128 + ks * 32 + ((lane >> 4) << 3);
  bfx8 o;
  #pragma unroll
  for (int i = 0; i < 8; ++i) o[i] = f2bf(s[i]);
  *reinterpret_cast<bfx8*>(pj.dst[j] + ((size_t)tid << 3)) = o;
}

// ---------------- CSR build (batched over 3 edge types) ----------------
struct CsrArgs { const int* edge[3]; int* counts[3]; int* offs[3]; u16* bucket[3]; };

__global__ __launch_bounds__(256) void k_hist(CsrArgs a) {
  int t = blockIdx.y;
  int tid = blockIdx.x * 256 + threadIdx.x;
  if (tid >= EE) return;
  atomicAdd(&a.counts[t][a.edge[t][EE + tid]], 1);
}

__global__ __launch_bounds__(1024) void k_scan(CsrArgs a) {
  const int* counts = a.counts[blockIdx.x];
  int* offs = a.offs[blockIdx.x];
  __shared__ int lds[1024];
  const int C = (NN + 1023) / 1024;   // 49
  int t = threadIdx.x;
  int base = t * C;
  int sum = 0;
  for (int i = 0; i < C; ++i) { int idx = base + i; if (idx < NN) sum += counts[idx]; }
  lds[t] = sum;
  __syncthreads();
  for (int off = 1; off < 1024; off <<= 1) {
    int v = (t >= off) ? lds[t - off] : 0;
    __syncthreads();
    lds[t] += v;
    __syncthreads();
  }
  int excl = lds[t] - sum;
  for (int i = 0; i < C; ++i) {
    int idx = base + i;
    if (idx < NN) { offs[idx] = excl; excl += counts[idx]; }
  }
}

__global__ __launch_bounds__(256) void k_fill(CsrArgs a) {
  int t = blockIdx.y;
  int tid = blockIdx.x * 256 + threadIdx.x;
  if (tid >= EE) return;
  int tgt = a.edge[t][EE + tid];
  int src = a.edge[t][tid];
  int pos = atomicAdd(&a.offs[t][tgt], 1);
  a.bucket[t][pos] = (u16)src;
}

// ---------------- gather: aggX[row] = sum of x rows (bf16 out, deep unroll) ----------------
struct GArgs {
  const int* offs[3]; const u16* bkt[3];
  const short* xsrc[3]; short* agg[3];
};

__global__ __launch_bounds__(256) void k_gather(GArgs a) {
  const int ty = blockIdx.y;
  const int* __restrict__ offs = a.offs[ty];
  const u16* __restrict__ bucket = a.bkt[ty];
  const short* __restrict__ xsrc = a.xsrc[ty];
  short* __restrict__ agg = a.agg[ty];
  int tid = threadIdx.x;
  int row = blockIdx.x * 32 + (tid >> 3);
  if (row >= NN) return;
  int c0 = (tid & 7) * 16;
  int start = row ? offs[row - 1] : 0;
  int end = offs[row];
  f32x4 s0 = (f32x4)(0.f), s1 = (f32x4)(0.f), s2 = (f32x4)(0.f), s3 = (f32x4)(0.f);
  int i = start;
  // main: 8 edges in flight
  for (; i + 8 <= end; i += 8) {
    const short* pp[8];
    #pragma unroll
    for (int m = 0; m < 8; ++m) pp[m] = xsrc + (size_t)bucket[i + m] * DD + c0;
    #pragma unroll
    for (int m = 0; m < 8; ++m) {
      bfx8 u = *reinterpret_cast<const bfx8*>(pp[m]);
      bfx8 v = *reinterpret_cast<const bfx8*>(pp[m] + 8);
      #pragma unroll
      for (int j = 0; j < 4; ++j) {
        s0[j] += bf2f(u[j]); s1[j] += bf2f(u[4+j]);
        s2[j] += bf2f(v[j]); s3[j] += bf2f(v[4+j]);
      }
    }
  }
  for (; i + 4 <= end; i += 4) {
    const short* pp[4];
    #pragma unroll
    for (int m = 0; m < 4; ++m) pp[m] = xsrc + (size_t)bucket[i + m] * DD + c0;
    #pragma unroll
    for (int m = 0; m < 4; ++m) {
      bfx8 u = *reinterpret_cast<const bfx8*>(pp[m]);
      bfx8 v = *reinterpret_cast<const bfx8*>(pp[m] + 8);
      #pragma unroll
      for (int j = 0; j < 4; ++j) {
        s0[j] += bf2f(u[j]); s1[j] += bf2f(u[4+j]);
        s2[j] += bf2f(v[j]); s3[j] += bf2f(v[4+j]);
      }
    }
  }
  for (; i < end; ++i) {
    const short* p = xsrc + (size_t)bucket[i] * DD + c0;
    bfx8 u = *reinterpret_cast<const bfx8*>(p), v = *reinterpret_cast<const bfx8*>(p + 8);
    #pragma unroll
    for (int j = 0; j < 4; ++j) {
      s0[j] += bf2f(u[j]); s1[j] += bf2f(u[4+j]);
      s2[j] += bf2f(v[j]); s3[j] += bf2f(v[4+j]);
    }
  }
  short* d = agg + (size_t)row * DD + c0;
  bfx8 o0, o1;
  #pragma unroll
  for (int j = 0; j < 4; ++j) {
    o0[j] = f2bf(s0[j]); o0[4+j] = f2bf(s1[j]);
    o1[j] = f2bf(s2[j]); o1[4+j] = f2bf(s3[j]);
  }
  *reinterpret_cast<bfx8*>(d) = o0;
  *reinterpret_cast<bfx8*>(d + 8) = o1;
}

// ---------------- GEMM + GRU, no LDS; block = 32 rows x 64 cols (wave = 16 cols) ----------------
// A-frag loads fully hoisted for MLP: 16 outstanding HBM loads per wave before MFMA section.
struct GGArgs {
  const short* aggX[2]; const short* xt[2];
  const short* wsp[2]; const short* combp[2]; const short* whhsp[2];
  const float* bih[2]; const float* bhh[2];
  float* out[2]; int mode[2];
};

__global__ __launch_bounds__(256, 3) void k_ggru(GGArgs a) {
  const int ty = blockIdx.y;
  const int wave = threadIdx.x >> 6, lane = threadIdx.x & 63;
  const int rbase = (blockIdx.x >> 1) * 32;
  const int colblk = blockIdx.x & 1;
  const int ctw = colblk * 4 + wave;          // this wave's 16-col tile index (0..7)
  const short* __restrict__ aggX = a.aggX[ty];
  const short* __restrict__ xt = a.xt[ty];
  const short* wsp = a.wsp[ty];
  const short* combp = a.combp[ty];
  const short* whhsp = a.whhsp[ty];

  // hoisted A-fragment loads (16 independent global loads in flight)
  bfx8 xf0[4], xf1[4], gf0[4], gf1[4];
  #pragma unroll
  for (int ks = 0; ks < 4; ++ks) {
    xf0[ks] = load_frag_clamp(xt,   rbase,      ks * 32, lane);
    xf1[ks] = load_frag_clamp(xt,   rbase + 16, ks * 32, lane);
    gf0[ks] = load_frag_clamp(aggX, rbase,      ks * 32, lane);
    gf1[ks] = load_frag_clamp(aggX, rbase + 16, ks * 32, lane);
  }

  f32x4 h[2], ai[2][3], ah[2][3];
  #pragma unroll
  for (int rf = 0; rf < 2; ++rf) {
    h[rf] = (f32x4)(0.f);
    #pragma unroll
    for (int g = 0; g < 3; ++g) { ai[rf][g] = (f32x4)(0.f); ah[rf][g] = (f32x4)(0.f); }
  }

  #pragma unroll
  for (int ks = 0; ks < 4; ++ks) {
    bfx8 bws = load_pk(wsp, ctw, ks, lane);
    h[0] = __builtin_amdgcn_mfma_f32_16x16x32_bf16(gf0[ks], bws, h[0], 0, 0, 0);
    h[1] = __builtin_amdgcn_mfma_f32_16x16x32_bf16(gf1[ks], bws, h[1], 0, 0, 0);
    #pragma unroll
    for (int g = 0; g < 3; ++g) {
      int ct = g * 8 + ctw;
      bfx8 bi = load_pk(combp, ct, ks, lane);
      bfx8 bh = load_pk(whhsp, ct, ks, lane);
      ai[0][g] = __builtin_amdgcn_mfma_f32_16x16x32_bf16(xf0[ks], bi, ai[0][g], 0, 0, 0);
      ai[1][g] = __builtin_amdgcn_mfma_f32_16x16x32_bf16(xf1[ks], bi, ai[1][g], 0, 0, 0);
      ah[0][g] = __builtin_amdgcn_mfma_f32_16x16x32_bf16(gf0[ks], bh, ah[0][g], 0, 0, 0);
      ah[1][g] = __builtin_amdgcn_mfma_f32_16x16x32_bf16(gf1[ks], bh, ah[1][g], 0, 0, 0);
    }
  }

  const float* bih = a.bih[ty];
  const float* bhh = a.bhh[ty];
  float* out = a.out[ty];
  const int mode = a.mode[ty];
  const int lq = (lane >> 4) << 2;
  const int col = ctw * 16 + (lane & 15);
  const float bir = bih[col], biz = bih[128 + col], bin = bih[256 + col];
  const float bhr = bhh[col], bhz = bhh[128 + col], bhn = bhh[256 + col];
  #pragma unroll
  for (int rf = 0; rf < 2; ++rf)
    #pragma unroll
    for (int q = 0; q < 4; ++q) {
      int r = rbase + rf * 16 + lq + q;
      if (r >= NN) continue;
      float ir = ai[rf][0][q] + bir, iz = ai[rf][1][q] + biz, in = ai[rf][2][q] + bin;
      float hr = ah[rf][0][q] + bhr, hz = ah[rf][1][q] + bhz, hn = ah[rf][2][q] + bhn;
      float rr = 1.f / (1.f + __expf(-(ir + hr)));
      float zz = 1.f / (1.f + __expf(-(iz + hz)));
      float t2 = in + rr * hn;
      float nn = 1.f - 2.f / (__expf(2.f * t2) + 1.f);   // tanh
      float hh = h[rf][q];
      float res = (1.f - zz) * nn + zz * hh;
      size_t o = (size_t)r * DD + col;
      if (mode == 0)      out[o] = fmaxf(res, 0.f);
      else if (mode == 1) out[o] = res;
      else                out[o] = fmaxf((out[o] + res) * 0.5f, 0.f);
    }
}

extern "C" void kernel_launch(void* const* d_in, const int* in_sizes, int n_in,
                              void* d_out, int out_size, void* d_ws, size_t ws_size,
                              hipStream_t stream) {
  const float* x_a = (const float*)d_in[0];
  const float* x_b = (const float*)d_in[1];
  const int* edges[3] = {(const int*)d_in[2], (const int*)d_in[3], (const int*)d_in[4]};
  const float *Ws[3], *Wt[3], *wih[3], *whh[3], *bih[3], *bhh[3];
  for (int e = 0; e < 3; ++e) {
    int b = 5 + e * 6;
    Ws[e]  = (const float*)d_in[b + 0];
    Wt[e]  = (const float*)d_in[b + 1];
    wih[e] = (const float*)d_in[b + 2];
    whh[e] = (const float*)d_in[b + 3];
    bih[e] = (const float*)d_in[b + 4];
    bhh[e] = (const float*)d_in[b + 5];
  }

  // workspace layout (~69 MB)
  char* ws = (char*)d_ws;
  short* xa_bf  = (short*)ws;                        // 12.8 MB
  short* xb_bf  = (short*)(ws + 12800000);           // 12.8 MB
  short* aggX   = (short*)(ws + 25600000);           // 3 x 12.8 MB
  int*   counts = (int*)(ws + 64000000);             // 3 x 200 KB
  int*   offs   = (int*)(ws + 64600000);             // 3 x 200 KB
  u16*   bucket = (u16*)(ws + 65200000);             // 3 x 1 MB
  short* pk     = (short*)(ws + 68200000);           // 3 x 224 KB
  short *wsp[3], *combp[3], *whhsp[3];
  short* aggp[3];
  int *countsp[3], *offsp[3]; u16* bktp[3];
  for (int e = 0; e < 3; ++e) {
    short* base = pk + (size_t)e * 114688;
    wsp[e] = base; combp[e] = base + 16384; whhsp[e] = base + 65536;
    aggp[e]   = aggX + (size_t)e * NN * DD;
    countsp[e] = counts + (size_t)e * 50000;
    offsp[e]   = offs + (size_t)e * 50000;
    bktp[e]    = bucket + (size_t)e * 500000;
  }

  // 1) convert x_a, x_b to bf16
  ConvJobs cj;
  cj.src[0] = x_a; cj.dst[0] = xa_bf;
  cj.src[1] = x_b; cj.dst[1] = xb_bf;
  hipLaunchKernelGGL(k_convert, dim3(6250, 2), dim3(256), 0, stream, cj);

  // 2) comb = wih@Wt, whhs = whh@Ws -> packed bf16 (6 jobs)
  CombJobs cb;
  for (int e = 0; e < 3; ++e) {
    cb.A[e] = wih[e];     cb.B[e] = Wt[e]; cb.out[e] = combp[e];
    cb.A[3 + e] = whh[e]; cb.B[3 + e] = Ws[e]; cb.out[3 + e] = whhsp[e];
  }
  hipLaunchKernelGGL(k_comb, dim3(192, 6), dim3(256), 0, stream, cb);

  // 3) pack Ws
  PackJobs pj;
  for (int e = 0; e < 3; ++e) { pj.src[e] = Ws[e]; pj.dst[e] = wsp[e]; pj.nct[e] = 8; }
  hipLaunchKernelGGL(k_pack, dim3(8, 3), dim3(256), 0, stream, pj);

  // 4) CSR build
  CsrArgs ca;
  for (int e = 0; e < 3; ++e) {
    ca.edge[e] = edges[e]; ca.counts[e] = countsp[e];
    ca.offs[e] = offsp[e]; ca.bucket[e] = bktp[e];
  }
  (void)hipMemsetAsync(counts, 0, 3 * 50000 * sizeof(int), stream);
  const int EB = (EE + 255) / 256;
  hipLaunchKernelGGL(k_hist, dim3(EB, 3), dim3(256), 0, stream, ca);
  hipLaunchKernelGGL(k_scan, dim3(3), dim3(1024), 0, stream, ca);
  hipLaunchKernelGGL(k_fill, dim3(EB, 3), dim3(256), 0, stream, ca);

  // 5) gather all 3 types
  GArgs ga;
  const short* srcb[3] = {xa_bf, xb_bf, xb_bf};
  for (int e = 0; e < 3; ++e) {
    ga.offs[e] = offsp[e]; ga.bkt[e] = bktp[e];
    ga.xsrc[e] = srcb[e];  ga.agg[e] = aggp[e];
  }
  hipLaunchKernelGGL(k_gather, dim3(ROWT, 3), dim3(256), 0, stream, ga);

  // 6) GEMM+GRU: dispatch A = {e1 -> out_b, e2 -> out_a raw}; dispatch B = {e3 -> out_a rmw}
  float* out_a = (float*)d_out;
  float* out_b = (float*)d_out + (size_t)NN * DD;

  GGArgs fa;
  fa.aggX[0] = aggp[0]; fa.xt[0] = xb_bf;
  fa.wsp[0] = wsp[0]; fa.combp[0] = combp[0]; fa.whhsp[0] = whhsp[0];
  fa.bih[0] = bih[0]; fa.bhh[0] = bhh[0];
  fa.out[0] = out_b; fa.mode[0] = 0;
  fa.aggX[1] = aggp[1]; fa.xt[1] = xa_bf;
  fa.wsp[1] = wsp[1]; fa.combp[1] = combp[1]; fa.whhsp[1] = whhsp[1];
  fa.bih[1] = bih[1]; fa.bhh[1] = bhh[1];
  fa.out[1] = out_a; fa.mode[1] = 1;
  hipLaunchKernelGGL(k_ggru, dim3(ROWT * 2, 2), dim3(256), 0, stream, fa);

  GGArgs fb;
  fb.aggX[0] = aggp[2]; fb.xt[0] = xa_bf;
  fb.wsp[0] = wsp[2]; fb.combp[0] = combp[2]; fb.whhsp[0] = whhsp[2];
  fb.bih[0] = bih[2]; fb.bhh[0] = bhh[2];
  fb.out[0] = out_a; fb.mode[0] = 2;
  fb.aggX[1] = fb.aggX[0]; fb.xt[1] = fb.xt[0];
  fb.wsp[1] = fb.wsp[0]; fb.combp[1] = fb.combp[0]; fb.whhsp[1] = fb.whhsp[0];
  fb.bih[1] = fb.bih[0]; fb.bhh[1] = fb.bhh[0];
  fb.out[1] = fb.out[0]; fb.mode[1] = fb.mode[0];
  hipLaunchKernelGGL(k_ggru, dim3(ROWT * 2, 1), dim3(256), 0, stream, fb);
}

// Round 11
// 403.559 us; speedup vs baseline: 1.3657x; 1.0667x over previous
//
#include <hip/hip_runtime.h>
#include <hip/hip_bf16.h>
#include <stdint.h>
#include <math.h>

#define NN 50000
#define DD 128
#define EE 500000
#define ROWT 1563   // ceil(NN/32)

typedef __attribute__((ext_vector_type(8))) short bfx8;
typedef __attribute__((ext_vector_type(4))) short bfx4;
typedef __attribute__((ext_vector_type(4))) float f32x4;
typedef unsigned short u16;

static __device__ __forceinline__ short f2bf(float f) {
  union { float f; uint32_t u; } v; v.f = f;
  uint32_t r = (v.u + 0x7fffu + ((v.u >> 16) & 1u)) >> 16;
  return (short)r;
}
static __device__ __forceinline__ float bf2f(short b) {
  union { uint32_t u; float f; } v; v.u = ((uint32_t)(uint16_t)b) << 16;
  return v.f;
}

// async global->LDS, 16B per lane; LDS dest = wave-uniform base + lane*16
static __device__ __forceinline__ void gl_lds16(const short* g, short* l) {
  __builtin_amdgcn_global_load_lds(
      (const __attribute__((address_space(1))) unsigned int*)g,
      (__attribute__((address_space(3))) unsigned int*)l, 16, 0, 0);
}

// B-fragment from packed weights: [ct][ks][64 lanes][8]
static __device__ __forceinline__ bfx8 load_pk(const short* p, int ct, int ks, int lane) {
  return *reinterpret_cast<const bfx8*>(p + ((((size_t)ct * 4 + ks) * 64 + lane) << 3));
}

// ---------------- convert fp32 -> bf16 (x_a, x_b) ----------------
struct ConvJobs { const float* src[2]; short* dst[2]; };

__global__ __launch_bounds__(256) void k_convert(ConvJobs jobs) {
  int j = blockIdx.y;
  const float* s = jobs.src[j];
  short* d = jobs.dst[j];
  int i = (blockIdx.x * 256 + threadIdx.x) * 4;
  if (i >= NN * DD) return;
  f32x4 v = *reinterpret_cast<const f32x4*>(s + i);
  bfx4 o;
  o[0]=f2bf(v[0]); o[1]=f2bf(v[1]); o[2]=f2bf(v[2]); o[3]=f2bf(v[3]);
  *reinterpret_cast<bfx4*>(d + i) = o;
}

// ------- P = A[384,128] @ B[128,128], written directly in packed fragment layout (bf16) -------
struct CombJobs { const float* A[6]; const float* B[6]; short* out[6]; };

__global__ __launch_bounds__(256) void k_comb(CombJobs cj) {
  int e = blockIdx.y;
  const float* A = cj.A[e];
  const float* B = cj.B[e];
  short* out = cj.out[e];
  int tid = blockIdx.x * 256 + threadIdx.x;   // 49152 = 384*128
  int i = tid >> 7, j = tid & 127;            // P[i][j]
  float acc = 0.f;
  #pragma unroll 4
  for (int k = 0; k < 128; ++k) acc += A[i * 128 + k] * B[k * 128 + j];
  int ct = i >> 4;
  int lane = (i & 15) | ((((j & 31) >> 3)) << 4);
  int ks = j >> 5;
  int elem = j & 7;
  out[(((size_t)(ct * 4 + ks) * 64 + lane) << 3) + elem] = f2bf(acc);
}

// ---------------- pack f32 matrix [R][128] into fragment layout bf16 ----------------
struct PackJobs { const float* src[3]; short* dst[3]; int nct[3]; };

__global__ __launch_bounds__(256) void k_pack(PackJobs pj) {
  int j = blockIdx.y;
  int tid = blockIdx.x * 256 + threadIdx.x;
  if (tid >= pj.nct[j] * 256) return;
  int lane = tid & 63, ks = (tid >> 6) & 3, ct = tid >> 8;
  const float* s = pj.src[j] + (size_t)(ct * 16 + (lane & 15)) * 128 + ks * 32 + ((lane >> 4) << 3);
  bfx8 o;
  #pragma unroll
  for (int i = 0; i < 8; ++i) o[i] = f2bf(s[i]);
  *reinterpret_cast<bfx8*>(pj.dst[j] + ((size_t)tid << 3)) = o;
}

// ---------------- CSR build (batched over 3 edge types) ----------------
struct CsrArgs { const int* edge[3]; int* counts[3]; int* offs[3]; u16* bucket[3]; };

__global__ __launch_bounds__(256) void k_hist(CsrArgs a) {
  int t = blockIdx.y;
  int tid = blockIdx.x * 256 + threadIdx.x;
  if (tid >= EE) return;
  atomicAdd(&a.counts[t][a.edge[t][EE + tid]], 1);
}

__global__ __launch_bounds__(1024) void k_scan(CsrArgs a) {
  const int* counts = a.counts[blockIdx.x];
  int* offs = a.offs[blockIdx.x];
  __shared__ int lds[1024];
  const int C = (NN + 1023) / 1024;   // 49
  int t = threadIdx.x;
  int base = t * C;
  int sum = 0;
  for (int i = 0; i < C; ++i) { int idx = base + i; if (idx < NN) sum += counts[idx]; }
  lds[t] = sum;
  __syncthreads();
  for (int off = 1; off < 1024; off <<= 1) {
    int v = (t >= off) ? lds[t - off] : 0;
    __syncthreads();
    lds[t] += v;
    __syncthreads();
  }
  int excl = lds[t] - sum;
  for (int i = 0; i < C; ++i) {
    int idx = base + i;
    if (idx < NN) { offs[idx] = excl; excl += counts[idx]; }
  }
}

__global__ __launch_bounds__(256) void k_fill(CsrArgs a) {
  int t = blockIdx.y;
  int tid = blockIdx.x * 256 + threadIdx.x;
  if (tid >= EE) return;
  int tgt = a.edge[t][EE + tid];
  int src = a.edge[t][tid];
  int pos = atomicAdd(&a.offs[t][tgt], 1);
  a.bucket[t][pos] = (u16)src;
}

// ---------------- gather: aggX[row] = sum of x rows (bf16 out, deep unroll) ----------------
struct GArgs {
  const int* offs[3]; const u16* bkt[3];
  const short* xsrc[3]; short* agg[3];
};

__global__ __launch_bounds__(256) void k_gather(GArgs a) {
  const int ty = blockIdx.y;
  const int* __restrict__ offs = a.offs[ty];
  const u16* __restrict__ bucket = a.bkt[ty];
  const short* __restrict__ xsrc = a.xsrc[ty];
  short* __restrict__ agg = a.agg[ty];
  int tid = threadIdx.x;
  int row = blockIdx.x * 32 + (tid >> 3);
  if (row >= NN) return;
  int c0 = (tid & 7) * 16;
  int start = row ? offs[row - 1] : 0;
  int end = offs[row];
  f32x4 s0 = (f32x4)(0.f), s1 = (f32x4)(0.f), s2 = (f32x4)(0.f), s3 = (f32x4)(0.f);
  int i = start;
  // main: 8 edges in flight
  for (; i + 8 <= end; i += 8) {
    const short* pp[8];
    #pragma unroll
    for (int m = 0; m < 8; ++m) pp[m] = xsrc + (size_t)bucket[i + m] * DD + c0;
    #pragma unroll
    for (int m = 0; m < 8; ++m) {
      bfx8 u = *reinterpret_cast<const bfx8*>(pp[m]);
      bfx8 v = *reinterpret_cast<const bfx8*>(pp[m] + 8);
      #pragma unroll
      for (int j = 0; j < 4; ++j) {
        s0[j] += bf2f(u[j]); s1[j] += bf2f(u[4+j]);
        s2[j] += bf2f(v[j]); s3[j] += bf2f(v[4+j]);
      }
    }
  }
  for (; i + 4 <= end; i += 4) {
    const short* pp[4];
    #pragma unroll
    for (int m = 0; m < 4; ++m) pp[m] = xsrc + (size_t)bucket[i + m] * DD + c0;
    #pragma unroll
    for (int m = 0; m < 4; ++m) {
      bfx8 u = *reinterpret_cast<const bfx8*>(pp[m]);
      bfx8 v = *reinterpret_cast<const bfx8*>(pp[m] + 8);
      #pragma unroll
      for (int j = 0; j < 4; ++j) {
        s0[j] += bf2f(u[j]); s1[j] += bf2f(u[4+j]);
        s2[j] += bf2f(v[j]); s3[j] += bf2f(v[4+j]);
      }
    }
  }
  for (; i < end; ++i) {
    const short* p = xsrc + (size_t)bucket[i] * DD + c0;
    bfx8 u = *reinterpret_cast<const bfx8*>(p), v = *reinterpret_cast<const bfx8*>(p + 8);
    #pragma unroll
    for (int j = 0; j < 4; ++j) {
      s0[j] += bf2f(u[j]); s1[j] += bf2f(u[4+j]);
      s2[j] += bf2f(v[j]); s3[j] += bf2f(v[4+j]);
    }
  }
  short* d = agg + (size_t)row * DD + c0;
  bfx8 o0, o1;
  #pragma unroll
  for (int j = 0; j < 4; ++j) {
    o0[j] = f2bf(s0[j]); o0[4+j] = f2bf(s1[j]);
    o1[j] = f2bf(s2[j]); o1[4+j] = f2bf(s3[j]);
  }
  *reinterpret_cast<bfx8*>(d) = o0;
  *reinterpret_cast<bfx8*>(d + 8) = o1;
}

// ---------------- GEMM + GRU; A-frags staged to LDS via global_load_lds ----------------
// block = 32 rows x 64 cols (wave = 16 cols). 16 frags x 1KB = 16KB LDS, fragment-ordered.
struct GGArgs {
  const short* aggX[2]; const short* xt[2];
  const short* wsp[2]; const short* combp[2]; const short* whhsp[2];
  const float* bih[2]; const float* bhh[2];
  float* out[2]; int mode[2];
};

__global__ __launch_bounds__(256) void k_ggru(GGArgs a) {
  __shared__ short lds[16 * 512];   // frag f at lds + f*512 shorts (1KB each)
  const int ty = blockIdx.y;
  const int wave = threadIdx.x >> 6, lane = threadIdx.x & 63;
  const int rbase = (blockIdx.x >> 1) * 32;
  const int colblk = blockIdx.x & 1;
  const int ctw = colblk * 4 + wave;          // this wave's 16-col tile index (0..7)
  const short* __restrict__ aggX = a.aggX[ty];
  const short* __restrict__ xt = a.xt[ty];
  const short* wsp = a.wsp[ty];
  const short* combp = a.combp[ty];
  const short* whhsp = a.whhsp[ty];

  // stage 16 A-fragments: f = buf*8 + half*4 + ks  (buf 0=xt, 1=aggX)
  #pragma unroll
  for (int i = 0; i < 4; ++i) {
    int f = wave * 4 + i;
    const short* src = (f & 8) ? aggX : xt;
    int r = rbase + ((f >> 2) & 1) * 16 + (lane & 15);
    if (r >= NN) r = NN - 1;
    const short* gp = src + (size_t)r * DD + (f & 3) * 32 + ((lane >> 4) << 3);
    gl_lds16(gp, lds + f * 512);
  }
  __syncthreads();

  f32x4 h[2], ai[2][3], ah[2][3];
  #pragma unroll
  for (int rf = 0; rf < 2; ++rf) {
    h[rf] = (f32x4)(0.f);
    #pragma unroll
    for (int g = 0; g < 3; ++g) { ai[rf][g] = (f32x4)(0.f); ah[rf][g] = (f32x4)(0.f); }
  }

  #pragma unroll
  for (int ks = 0; ks < 4; ++ks) {
    bfx8 x0 = *reinterpret_cast<const bfx8*>(lds + (0  + ks) * 512 + lane * 8);
    bfx8 x1 = *reinterpret_cast<const bfx8*>(lds + (4  + ks) * 512 + lane * 8);
    bfx8 g0 = *reinterpret_cast<const bfx8*>(lds + (8  + ks) * 512 + lane * 8);
    bfx8 g1 = *reinterpret_cast<const bfx8*>(lds + (12 + ks) * 512 + lane * 8);
    bfx8 bws = load_pk(wsp, ctw, ks, lane);
    h[0] = __builtin_amdgcn_mfma_f32_16x16x32_bf16(g0, bws, h[0], 0, 0, 0);
    h[1] = __builtin_amdgcn_mfma_f32_16x16x32_bf16(g1, bws, h[1], 0, 0, 0);
    #pragma unroll
    for (int g = 0; g < 3; ++g) {
      int ct = g * 8 + ctw;
      bfx8 bi = load_pk(combp, ct, ks, lane);
      bfx8 bh = load_pk(whhsp, ct, ks, lane);
      ai[0][g] = __builtin_amdgcn_mfma_f32_16x16x32_bf16(x0, bi, ai[0][g], 0, 0, 0);
      ai[1][g] = __builtin_amdgcn_mfma_f32_16x16x32_bf16(x1, bi, ai[1][g], 0, 0, 0);
      ah[0][g] = __builtin_amdgcn_mfma_f32_16x16x32_bf16(g0, bh, ah[0][g], 0, 0, 0);
      ah[1][g] = __builtin_amdgcn_mfma_f32_16x16x32_bf16(g1, bh, ah[1][g], 0, 0, 0);
    }
  }

  const float* bih = a.bih[ty];
  const float* bhh = a.bhh[ty];
  float* out = a.out[ty];
  const int mode = a.mode[ty];
  const int lq = (lane >> 4) << 2;
  const int col = ctw * 16 + (lane & 15);
  const float bir = bih[col], biz = bih[128 + col], bin = bih[256 + col];
  const float bhr = bhh[col], bhz = bhh[128 + col], bhn = bhh[256 + col];
  #pragma unroll
  for (int rf = 0; rf < 2; ++rf)
    #pragma unroll
    for (int q = 0; q < 4; ++q) {
      int r = rbase + rf * 16 + lq + q;
      if (r >= NN) continue;
      float ir = ai[rf][0][q] + bir, iz = ai[rf][1][q] + biz, in = ai[rf][2][q] + bin;
      float hr = ah[rf][0][q] + bhr, hz = ah[rf][1][q] + bhz, hn = ah[rf][2][q] + bhn;
      float rr = 1.f / (1.f + __expf(-(ir + hr)));
      float zz = 1.f / (1.f + __expf(-(iz + hz)));
      float t2 = in + rr * hn;
      float nn = 1.f - 2.f / (__expf(2.f * t2) + 1.f);   // tanh
      float hh = h[rf][q];
      float res = (1.f - zz) * nn + zz * hh;
      size_t o = (size_t)r * DD + col;
      if (mode == 0)      out[o] = fmaxf(res, 0.f);
      else if (mode == 1) out[o] = res;
      else                out[o] = fmaxf((out[o] + res) * 0.5f, 0.f);
    }
}

extern "C" void kernel_launch(void* const* d_in, const int* in_sizes, int n_in,
                              void* d_out, int out_size, void* d_ws, size_t ws_size,
                              hipStream_t stream) {
  const float* x_a = (const float*)d_in[0];
  const float* x_b = (const float*)d_in[1];
  const int* edges[3] = {(const int*)d_in[2], (const int*)d_in[3], (const int*)d_in[4]};
  const float *Ws[3], *Wt[3], *wih[3], *whh[3], *bih[3], *bhh[3];
  for (int e = 0; e < 3; ++e) {
    int b = 5 + e * 6;
    Ws[e]  = (const float*)d_in[b + 0];
    Wt[e]  = (const float*)d_in[b + 1];
    wih[e] = (const float*)d_in[b + 2];
    whh[e] = (const float*)d_in[b + 3];
    bih[e] = (const float*)d_in[b + 4];
    bhh[e] = (const float*)d_in[b + 5];
  }

  // workspace layout (~69 MB)
  char* ws = (char*)d_ws;
  short* xa_bf  = (short*)ws;                        // 12.8 MB
  short* xb_bf  = (short*)(ws + 12800000);           // 12.8 MB
  short* aggX   = (short*)(ws + 25600000);           // 3 x 12.8 MB
  int*   counts = (int*)(ws + 64000000);             // 3 x 200 KB
  int*   offs   = (int*)(ws + 64600000);             // 3 x 200 KB
  u16*   bucket = (u16*)(ws + 65200000);             // 3 x 1 MB
  short* pk     = (short*)(ws + 68200000);           // 3 x 224 KB
  short *wsp[3], *combp[3], *whhsp[3];
  short* aggp[3];
  int *countsp[3], *offsp[3]; u16* bktp[3];
  for (int e = 0; e < 3; ++e) {
    short* base = pk + (size_t)e * 114688;
    wsp[e] = base; combp[e] = base + 16384; whhsp[e] = base + 65536;
    aggp[e]   = aggX + (size_t)e * NN * DD;
    countsp[e] = counts + (size_t)e * 50000;
    offsp[e]   = offs + (size_t)e * 50000;
    bktp[e]    = bucket + (size_t)e * 500000;
  }

  // 1) convert x_a, x_b to bf16
  ConvJobs cj;
  cj.src[0] = x_a; cj.dst[0] = xa_bf;
  cj.src[1] = x_b; cj.dst[1] = xb_bf;
  hipLaunchKernelGGL(k_convert, dim3(6250, 2), dim3(256), 0, stream, cj);

  // 2) comb = wih@Wt, whhs = whh@Ws -> packed bf16 (6 jobs)
  CombJobs cb;
  for (int e = 0; e < 3; ++e) {
    cb.A[e] = wih[e];     cb.B[e] = Wt[e]; cb.out[e] = combp[e];
    cb.A[3 + e] = whh[e]; cb.B[3 + e] = Ws[e]; cb.out[3 + e] = whhsp[e];
  }
  hipLaunchKernelGGL(k_comb, dim3(192, 6), dim3(256), 0, stream, cb);

  // 3) pack Ws
  PackJobs pj;
  for (int e = 0; e < 3; ++e) { pj.src[e] = Ws[e]; pj.dst[e] = wsp[e]; pj.nct[e] = 8; }
  hipLaunchKernelGGL(k_pack, dim3(8, 3), dim3(256), 0, stream, pj);

  // 4) CSR build
  CsrArgs ca;
  for (int e = 0; e < 3; ++e) {
    ca.edge[e] = edges[e]; ca.counts[e] = countsp[e];
    ca.offs[e] = offsp[e]; ca.bucket[e] = bktp[e];
  }
  (void)hipMemsetAsync(counts, 0, 3 * 50000 * sizeof(int), stream);
  const int EB = (EE + 255) / 256;
  hipLaunchKernelGGL(k_hist, dim3(EB, 3), dim3(256), 0, stream, ca);
  hipLaunchKernelGGL(k_scan, dim3(3), dim3(1024), 0, stream, ca);
  hipLaunchKernelGGL(k_fill, dim3(EB, 3), dim3(256), 0, stream, ca);

  // 5) gather all 3 types
  GArgs ga;
  const short* srcb[3] = {xa_bf, xb_bf, xb_bf};
  for (int e = 0; e < 3; ++e) {
    ga.offs[e] = offsp[e]; ga.bkt[e] = bktp[e];
    ga.xsrc[e] = srcb[e];  ga.agg[e] = aggp[e];
  }
  hipLaunchKernelGGL(k_gather, dim3(ROWT, 3), dim3(256), 0, stream, ga);

  // 6) GEMM+GRU: dispatch A = {e1 -> out_b, e2 -> out_a raw}; dispatch B = {e3 -> out_a rmw}
  float* out_a = (float*)d_out;
  float* out_b = (float*)d_out + (size_t)NN * DD;

  GGArgs fa;
  fa.aggX[0] = aggp[0]; fa.xt[0] = xb_bf;
  fa.wsp[0] = wsp[0]; fa.combp[0] = combp[0]; fa.whhsp[0] = whhsp[0];
  fa.bih[0] = bih[0]; fa.bhh[0] = bhh[0];
  fa.out[0] = out_b; fa.mode[0] = 0;
  fa.aggX[1] = aggp[1]; fa.xt[1] = xa_bf;
  fa.wsp[1] = wsp[1]; fa.combp[1] = combp[1]; fa.whhsp[1] = whhsp[1];
  fa.bih[1] = bih[1]; fa.bhh[1] = bhh[1];
  fa.out[1] = out_a; fa.mode[1] = 1;
  hipLaunchKernelGGL(k_ggru, dim3(ROWT * 2, 2), dim3(256), 0, stream, fa);

  GGArgs fb;
  fb.aggX[0] = aggp[2]; fb.xt[0] = xa_bf;
  fb.wsp[0] = wsp[2]; fb.combp[0] = combp[2]; fb.whhsp[0] = whhsp[2];
  fb.bih[0] = bih[2]; fb.bhh[0] = bhh[2];
  fb.out[0] = out_a; fb.mode[0] = 2;
  fb.aggX[1] = fb.aggX[0]; fb.xt[1] = fb.xt[0];
  fb.wsp[1] = fb.wsp[0]; fb.combp[1] = fb.combp[0]; fb.whhsp[1] = fb.whhsp[0];
  fb.bih[1] = fb.bih[0]; fb.bhh[1] = fb.bhh[0];
  fb.out[1] = fb.out[0]; fb.mode[1] = fb.mode[0];
  hipLaunchKernelGGL(k_ggru, dim3(ROWT * 2, 1), dim3(256), 0, stream, fb);
}

// Round 12
// 331.080 us; speedup vs baseline: 1.6646x; 1.2189x over previous
//
#include <hip/hip_runtime.h>
#include <hip/hip_bf16.h>
#include <stdint.h>
#include <math.h>

#define NN 50000
#define DD 128
#define EE 500000
#define ROWT 1563   // ceil(NN/32)
#define SBLK 49     // ceil(NN/1024) scan blocks per type

typedef __attribute__((ext_vector_type(8))) short bfx8;
typedef __attribute__((ext_vector_type(4))) short bfx4;
typedef __attribute__((ext_vector_type(4))) float f32x4;
typedef __attribute__((ext_vector_type(4))) int i32x4;
typedef unsigned short u16;

static __device__ __forceinline__ short f2bf(float f) {
  union { float f; uint32_t u; } v; v.f = f;
  uint32_t r = (v.u + 0x7fffu + ((v.u >> 16) & 1u)) >> 16;
  return (short)r;
}
static __device__ __forceinline__ float bf2f(short b) {
  union { uint32_t u; float f; } v; v.u = ((uint32_t)(uint16_t)b) << 16;
  return v.f;
}

// async global->LDS, 16B per lane; LDS dest = wave-uniform base + lane*16
static __device__ __forceinline__ void gl_lds16(const short* g, short* l) {
  __builtin_amdgcn_global_load_lds(
      (const __attribute__((address_space(1))) unsigned int*)g,
      (__attribute__((address_space(3))) unsigned int*)l, 16, 0, 0);
}

// B-fragment from packed weights: [ct][ks][64 lanes][8]
static __device__ __forceinline__ bfx8 load_pk(const short* p, int ct, int ks, int lane) {
  return *reinterpret_cast<const bfx8*>(p + ((((size_t)ct * 4 + ks) * 64 + lane) << 3));
}

// ---------------- convert fp32 -> bf16 (x_a, x_b) ----------------
struct ConvJobs { const float* src[2]; short* dst[2]; };

__global__ __launch_bounds__(256) void k_convert(ConvJobs jobs) {
  int j = blockIdx.y;
  const float* s = jobs.src[j];
  short* d = jobs.dst[j];
  int i = (blockIdx.x * 256 + threadIdx.x) * 4;
  if (i >= NN * DD) return;
  f32x4 v = *reinterpret_cast<const f32x4*>(s + i);
  bfx4 o;
  o[0]=f2bf(v[0]); o[1]=f2bf(v[1]); o[2]=f2bf(v[2]); o[3]=f2bf(v[3]);
  *reinterpret_cast<bfx4*>(d + i) = o;
}

// ------- P = A[384,128] @ B[128,128], written directly in packed fragment layout (bf16) -------
struct CombJobs { const float* A[6]; const float* B[6]; short* out[6]; };

__global__ __launch_bounds__(256) void k_comb(CombJobs cj) {
  int e = blockIdx.y;
  const float* A = cj.A[e];
  const float* B = cj.B[e];
  short* out = cj.out[e];
  int tid = blockIdx.x * 256 + threadIdx.x;   // 49152 = 384*128
  int i = tid >> 7, j = tid & 127;            // P[i][j]
  float acc = 0.f;
  #pragma unroll 4
  for (int k = 0; k < 128; ++k) acc += A[i * 128 + k] * B[k * 128 + j];
  int ct = i >> 4;
  int lane = (i & 15) | ((((j & 31) >> 3)) << 4);
  int ks = j >> 5;
  int elem = j & 7;
  out[(((size_t)(ct * 4 + ks) * 64 + lane) << 3) + elem] = f2bf(acc);
}

// ---------------- pack f32 matrix [R][128] into fragment layout bf16 ----------------
struct PackJobs { const float* src[3]; short* dst[3]; int nct[3]; };

__global__ __launch_bounds__(256) void k_pack(PackJobs pj) {
  int j = blockIdx.y;
  int tid = blockIdx.x * 256 + threadIdx.x;
  if (tid >= pj.nct[j] * 256) return;
  int lane = tid & 63, ks = (tid >> 6) & 3, ct = tid >> 8;
  const float* s = pj.src[j] + (size_t)(ct * 16 + (lane & 15)) * 128 + ks * 32 + ((lane >> 4) << 3);
  bfx8 o;
  #pragma unroll
  for (int i = 0; i < 8; ++i) o[i] = f2bf(s[i]);
  *reinterpret_cast<bfx8*>(pj.dst[j] + ((size_t)tid << 3)) = o;
}

// ---------------- CSR build (batched over 3 edge types) ----------------
struct CsrArgs { const int* edge[3]; int* counts[3]; int* offs[3]; u16* bucket[3]; int* bsums; };

__global__ __launch_bounds__(256) void k_hist(CsrArgs a) {
  int t = blockIdx.y;
  int tid = blockIdx.x * 256 + threadIdx.x;
  if (tid >= EE) return;
  atomicAdd(&a.counts[t][a.edge[t][EE + tid]], 1);
}

// scanA: per-block (1024 elems) local exclusive scan; block totals -> bsums[type][blk]
__global__ __launch_bounds__(256) void k_scanA(CsrArgs a) {
  __shared__ int lds[256];
  const int t = blockIdx.y;
  const int blk = blockIdx.x;
  const int tid = threadIdx.x;
  const int* counts = a.counts[t];
  int* offs = a.offs[t];
  int idx = blk * 1024 + tid * 4;
  i32x4 c = (i32x4)(0);
  if (idx < NN) c = *reinterpret_cast<const i32x4*>(counts + idx);   // NN%4==0: all-or-nothing
  int s = c[0] + c[1] + c[2] + c[3];
  lds[tid] = s;
  __syncthreads();
  #pragma unroll
  for (int off = 1; off < 256; off <<= 1) {
    int v = (tid >= off) ? lds[tid - off] : 0;
    __syncthreads();
    lds[tid] += v;
    __syncthreads();
  }
  int excl = lds[tid] - s;          // exclusive prefix of this thread within block
  if (idx < NN) {
    i32x4 o;
    o[0] = excl;
    o[1] = o[0] + c[0];
    o[2] = o[1] + c[1];
    o[3] = o[2] + c[2];
    *reinterpret_cast<i32x4*>(offs + idx) = o;
  }
  if (tid == 255) a.bsums[t * SBLK + blk] = lds[255];
}

// scanB: add preceding block totals
__global__ __launch_bounds__(256) void k_scanB(CsrArgs a) {
  const int t = blockIdx.y;
  const int blk = blockIdx.x;
  if (blk == 0) return;
  const int tid = threadIdx.x;
  const int* bs = a.bsums + t * SBLK;
  int add = 0;
  for (int i = 0; i < blk; ++i) add += bs[i];
  int idx = blk * 1024 + tid * 4;
  if (idx >= NN) return;
  int* offs = a.offs[t];
  i32x4 o = *reinterpret_cast<i32x4*>(offs + idx);
  o[0] += add; o[1] += add; o[2] += add; o[3] += add;
  *reinterpret_cast<i32x4*>(offs + idx) = o;
}

__global__ __launch_bounds__(256) void k_fill(CsrArgs a) {
  int t = blockIdx.y;
  int tid = blockIdx.x * 256 + threadIdx.x;
  if (tid >= EE) return;
  int tgt = a.edge[t][EE + tid];
  int src = a.edge[t][tid];
  int pos = atomicAdd(&a.offs[t][tgt], 1);
  a.bucket[t][pos] = (u16)src;
}

// ---------------- gather: aggX[row] = sum of x rows (bf16 out, deep unroll) ----------------
struct GArgs {
  const int* offs[3]; const u16* bkt[3];
  const short* xsrc[3]; short* agg[3];
};

__global__ __launch_bounds__(256) void k_gather(GArgs a) {
  const int ty = blockIdx.y;
  const int* __restrict__ offs = a.offs[ty];
  const u16* __restrict__ bucket = a.bkt[ty];
  const short* __restrict__ xsrc = a.xsrc[ty];
  short* __restrict__ agg = a.agg[ty];
  int tid = threadIdx.x;
  int row = blockIdx.x * 32 + (tid >> 3);
  if (row >= NN) return;
  int c0 = (tid & 7) * 16;
  int start = row ? offs[row - 1] : 0;
  int end = offs[row];
  f32x4 s0 = (f32x4)(0.f), s1 = (f32x4)(0.f), s2 = (f32x4)(0.f), s3 = (f32x4)(0.f);
  int i = start;
  // main: 8 edges in flight
  for (; i + 8 <= end; i += 8) {
    const short* pp[8];
    #pragma unroll
    for (int m = 0; m < 8; ++m) pp[m] = xsrc + (size_t)bucket[i + m] * DD + c0;
    #pragma unroll
    for (int m = 0; m < 8; ++m) {
      bfx8 u = *reinterpret_cast<const bfx8*>(pp[m]);
      bfx8 v = *reinterpret_cast<const bfx8*>(pp[m] + 8);
      #pragma unroll
      for (int j = 0; j < 4; ++j) {
        s0[j] += bf2f(u[j]); s1[j] += bf2f(u[4+j]);
        s2[j] += bf2f(v[j]); s3[j] += bf2f(v[4+j]);
      }
    }
  }
  for (; i + 4 <= end; i += 4) {
    const short* pp[4];
    #pragma unroll
    for (int m = 0; m < 4; ++m) pp[m] = xsrc + (size_t)bucket[i + m] * DD + c0;
    #pragma unroll
    for (int m = 0; m < 4; ++m) {
      bfx8 u = *reinterpret_cast<const bfx8*>(pp[m]);
      bfx8 v = *reinterpret_cast<const bfx8*>(pp[m] + 8);
      #pragma unroll
      for (int j = 0; j < 4; ++j) {
        s0[j] += bf2f(u[j]); s1[j] += bf2f(u[4+j]);
        s2[j] += bf2f(v[j]); s3[j] += bf2f(v[4+j]);
      }
    }
  }
  for (; i < end; ++i) {
    const short* p = xsrc + (size_t)bucket[i] * DD + c0;
    bfx8 u = *reinterpret_cast<const bfx8*>(p), v = *reinterpret_cast<const bfx8*>(p + 8);
    #pragma unroll
    for (int j = 0; j < 4; ++j) {
      s0[j] += bf2f(u[j]); s1[j] += bf2f(u[4+j]);
      s2[j] += bf2f(v[j]); s3[j] += bf2f(v[4+j]);
    }
  }
  short* d = agg + (size_t)row * DD + c0;
  bfx8 o0, o1;
  #pragma unroll
  for (int j = 0; j < 4; ++j) {
    o0[j] = f2bf(s0[j]); o0[4+j] = f2bf(s1[j]);
    o1[j] = f2bf(s2[j]); o1[4+j] = f2bf(s3[j]);
  }
  *reinterpret_cast<bfx8*>(d) = o0;
  *reinterpret_cast<bfx8*>(d + 8) = o1;
}

// ---------------- GEMM + GRU; A-frags staged to LDS via global_load_lds ----------------
struct GGArgs {
  const short* aggX[2]; const short* xt[2];
  const short* wsp[2]; const short* combp[2]; const short* whhsp[2];
  const float* bih[2]; const float* bhh[2];
  float* out[2]; int mode[2];
};

__global__ __launch_bounds__(256) void k_ggru(GGArgs a) {
  __shared__ short lds[16 * 512];   // frag f at lds + f*512 shorts (1KB each)
  const int ty = blockIdx.y;
  const int wave = threadIdx.x >> 6, lane = threadIdx.x & 63;
  const int rbase = (blockIdx.x >> 1) * 32;
  const int colblk = blockIdx.x & 1;
  const int ctw = colblk * 4 + wave;          // this wave's 16-col tile index (0..7)
  const short* __restrict__ aggX = a.aggX[ty];
  const short* __restrict__ xt = a.xt[ty];
  const short* wsp = a.wsp[ty];
  const short* combp = a.combp[ty];
  const short* whhsp = a.whhsp[ty];

  // stage 16 A-fragments: f = buf*8 + half*4 + ks  (buf 0=xt, 1=aggX)
  #pragma unroll
  for (int i = 0; i < 4; ++i) {
    int f = wave * 4 + i;
    const short* src = (f & 8) ? aggX : xt;
    int r = rbase + ((f >> 2) & 1) * 16 + (lane & 15);
    if (r >= NN) r = NN - 1;
    const short* gp = src + (size_t)r * DD + (f & 3) * 32 + ((lane >> 4) << 3);
    gl_lds16(gp, lds + f * 512);
  }
  __syncthreads();

  f32x4 h[2], ai[2][3], ah[2][3];
  #pragma unroll
  for (int rf = 0; rf < 2; ++rf) {
    h[rf] = (f32x4)(0.f);
    #pragma unroll
    for (int g = 0; g < 3; ++g) { ai[rf][g] = (f32x4)(0.f); ah[rf][g] = (f32x4)(0.f); }
  }

  #pragma unroll
  for (int ks = 0; ks < 4; ++ks) {
    bfx8 x0 = *reinterpret_cast<const bfx8*>(lds + (0  + ks) * 512 + lane * 8);
    bfx8 x1 = *reinterpret_cast<const bfx8*>(lds + (4  + ks) * 512 + lane * 8);
    bfx8 g0 = *reinterpret_cast<const bfx8*>(lds + (8  + ks) * 512 + lane * 8);
    bfx8 g1 = *reinterpret_cast<const bfx8*>(lds + (12 + ks) * 512 + lane * 8);
    bfx8 bws = load_pk(wsp, ctw, ks, lane);
    h[0] = __builtin_amdgcn_mfma_f32_16x16x32_bf16(g0, bws, h[0], 0, 0, 0);
    h[1] = __builtin_amdgcn_mfma_f32_16x16x32_bf16(g1, bws, h[1], 0, 0, 0);
    #pragma unroll
    for (int g = 0; g < 3; ++g) {
      int ct = g * 8 + ctw;
      bfx8 bi = load_pk(combp, ct, ks, lane);
      bfx8 bh = load_pk(whhsp, ct, ks, lane);
      ai[0][g] = __builtin_amdgcn_mfma_f32_16x16x32_bf16(x0, bi, ai[0][g], 0, 0, 0);
      ai[1][g] = __builtin_amdgcn_mfma_f32_16x16x32_bf16(x1, bi, ai[1][g], 0, 0, 0);
      ah[0][g] = __builtin_amdgcn_mfma_f32_16x16x32_bf16(g0, bh, ah[0][g], 0, 0, 0);
      ah[1][g] = __builtin_amdgcn_mfma_f32_16x16x32_bf16(g1, bh, ah[1][g], 0, 0, 0);
    }
  }

  const float* bih = a.bih[ty];
  const float* bhh = a.bhh[ty];
  float* out = a.out[ty];
  const int mode = a.mode[ty];
  const int lq = (lane >> 4) << 2;
  const int col = ctw * 16 + (lane & 15);
  const float bir = bih[col], biz = bih[128 + col], bin = bih[256 + col];
  const float bhr = bhh[col], bhz = bhh[128 + col], bhn = bhh[256 + col];
  #pragma unroll
  for (int rf = 0; rf < 2; ++rf)
    #pragma unroll
    for (int q = 0; q < 4; ++q) {
      int r = rbase + rf * 16 + lq + q;
      if (r >= NN) continue;
      float ir = ai[rf][0][q] + bir, iz = ai[rf][1][q] + biz, in = ai[rf][2][q] + bin;
      float hr = ah[rf][0][q] + bhr, hz = ah[rf][1][q] + bhz, hn = ah[rf][2][q] + bhn;
      float rr = 1.f / (1.f + __expf(-(ir + hr)));
      float zz = 1.f / (1.f + __expf(-(iz + hz)));
      float t2 = in + rr * hn;
      float nn = 1.f - 2.f / (__expf(2.f * t2) + 1.f);   // tanh
      float hh = h[rf][q];
      float res = (1.f - zz) * nn + zz * hh;
      size_t o = (size_t)r * DD + col;
      if (mode == 0)      out[o] = fmaxf(res, 0.f);
      else if (mode == 1) out[o] = res;
      else                out[o] = fmaxf((out[o] + res) * 0.5f, 0.f);
    }
}

extern "C" void kernel_launch(void* const* d_in, const int* in_sizes, int n_in,
                              void* d_out, int out_size, void* d_ws, size_t ws_size,
                              hipStream_t stream) {
  const float* x_a = (const float*)d_in[0];
  const float* x_b = (const float*)d_in[1];
  const int* edges[3] = {(const int*)d_in[2], (const int*)d_in[3], (const int*)d_in[4]};
  const float *Ws[3], *Wt[3], *wih[3], *whh[3], *bih[3], *bhh[3];
  for (int e = 0; e < 3; ++e) {
    int b = 5 + e * 6;
    Ws[e]  = (const float*)d_in[b + 0];
    Wt[e]  = (const float*)d_in[b + 1];
    wih[e] = (const float*)d_in[b + 2];
    whh[e] = (const float*)d_in[b + 3];
    bih[e] = (const float*)d_in[b + 4];
    bhh[e] = (const float*)d_in[b + 5];
  }

  // workspace layout (~69 MB)
  char* ws = (char*)d_ws;
  short* xa_bf  = (short*)ws;                        // 12.8 MB
  short* xb_bf  = (short*)(ws + 12800000);           // 12.8 MB
  short* aggX   = (short*)(ws + 25600000);           // 3 x 12.8 MB
  int*   counts = (int*)(ws + 64000000);             // 3 x 200 KB
  int*   offs   = (int*)(ws + 64600000);             // 3 x 200 KB
  u16*   bucket = (u16*)(ws + 65200000);             // 3 x 1 MB
  short* pk     = (short*)(ws + 68200000);           // 3 x 224 KB
  int*   bsums  = (int*)(ws + 68900000);             // 3 x 49 ints
  short *wsp[3], *combp[3], *whhsp[3];
  short* aggp[3];
  int *countsp[3], *offsp[3]; u16* bktp[3];
  for (int e = 0; e < 3; ++e) {
    short* base = pk + (size_t)e * 114688;
    wsp[e] = base; combp[e] = base + 16384; whhsp[e] = base + 65536;
    aggp[e]   = aggX + (size_t)e * NN * DD;
    countsp[e] = counts + (size_t)e * 50000;
    offsp[e]   = offs + (size_t)e * 50000;
    bktp[e]    = bucket + (size_t)e * 500000;
  }

  // 1) convert x_a, x_b to bf16
  ConvJobs cj;
  cj.src[0] = x_a; cj.dst[0] = xa_bf;
  cj.src[1] = x_b; cj.dst[1] = xb_bf;
  hipLaunchKernelGGL(k_convert, dim3(6250, 2), dim3(256), 0, stream, cj);

  // 2) comb = wih@Wt, whhs = whh@Ws -> packed bf16 (6 jobs)
  CombJobs cb;
  for (int e = 0; e < 3; ++e) {
    cb.A[e] = wih[e];     cb.B[e] = Wt[e]; cb.out[e] = combp[e];
    cb.A[3 + e] = whh[e]; cb.B[3 + e] = Ws[e]; cb.out[3 + e] = whhsp[e];
  }
  hipLaunchKernelGGL(k_comb, dim3(192, 6), dim3(256), 0, stream, cb);

  // 3) pack Ws
  PackJobs pj;
  for (int e = 0; e < 3; ++e) { pj.src[e] = Ws[e]; pj.dst[e] = wsp[e]; pj.nct[e] = 8; }
  hipLaunchKernelGGL(k_pack, dim3(8, 3), dim3(256), 0, stream, pj);

  // 4) CSR build
  CsrArgs ca;
  for (int e = 0; e < 3; ++e) {
    ca.edge[e] = edges[e]; ca.counts[e] = countsp[e];
    ca.offs[e] = offsp[e]; ca.bucket[e] = bktp[e];
  }
  ca.bsums = bsums;
  (void)hipMemsetAsync(counts, 0, 3 * 50000 * sizeof(int), stream);
  const int EB = (EE + 255) / 256;
  hipLaunchKernelGGL(k_hist, dim3(EB, 3), dim3(256), 0, stream, ca);
  hipLaunchKernelGGL(k_scanA, dim3(SBLK, 3), dim3(256), 0, stream, ca);
  hipLaunchKernelGGL(k_scanB, dim3(SBLK, 3), dim3(256), 0, stream, ca);
  hipLaunchKernelGGL(k_fill, dim3(EB, 3), dim3(256), 0, stream, ca);

  // 5) gather all 3 types
  GArgs ga;
  const short* srcb[3] = {xa_bf, xb_bf, xb_bf};
  for (int e = 0; e < 3; ++e) {
    ga.offs[e] = offsp[e]; ga.bkt[e] = bktp[e];
    ga.xsrc[e] = srcb[e];  ga.agg[e] = aggp[e];
  }
  hipLaunchKernelGGL(k_gather, dim3(ROWT, 3), dim3(256), 0, stream, ga);

  // 6) GEMM+GRU: dispatch A = {e1 -> out_b, e2 -> out_a raw}; dispatch B = {e3 -> out_a rmw}
  float* out_a = (float*)d_out;
  float* out_b = (float*)d_out + (size_t)NN * DD;

  GGArgs fa;
  fa.aggX[0] = aggp[0]; fa.xt[0] = xb_bf;
  fa.wsp[0] = wsp[0]; fa.combp[0] = combp[0]; fa.whhsp[0] = whhsp[0];
  fa.bih[0] = bih[0]; fa.bhh[0] = bhh[0];
  fa.out[0] = out_b; fa.mode[0] = 0;
  fa.aggX[1] = aggp[1]; fa.xt[1] = xa_bf;
  fa.wsp[1] = wsp[1]; fa.combp[1] = combp[1]; fa.whhsp[1] = whhsp[1];
  fa.bih[1] = bih[1]; fa.bhh[1] = bhh[1];
  fa.out[1] = out_a; fa.mode[1] = 1;
  hipLaunchKernelGGL(k_ggru, dim3(ROWT * 2, 2), dim3(256), 0, stream, fa);

  GGArgs fb;
  fb.aggX[0] = aggp[2]; fb.xt[0] = xa_bf;
  fb.wsp[0] = wsp[2]; fb.combp[0] = combp[2]; fb.whhsp[0] = whhsp[2];
  fb.bih[0] = bih[2]; fb.bhh[0] = bhh[2];
  fb.out[0] = out_a; fb.mode[0] = 2;
  fb.aggX[1] = fb.aggX[0]; fb.xt[1] = fb.xt[0];
  fb.wsp[1] = fb.wsp[0]; fb.combp[1] = fb.combp[0]; fb.whhsp[1] = fb.whhsp[0];
  fb.bih[1] = fb.bih[0]; fb.bhh[1] = fb.bhh[0];
  fb.out[1] = fb.out[0]; fb.mode[1] = fb.mode[0];
  hipLaunchKernelGGL(k_ggru, dim3(ROWT * 2, 1), dim3(256), 0, stream, fb);
}